// Round 6
// baseline (1036.540 us; speedup 1.0000x reference)
//
#include <hip/hip_runtime.h>
#include <hip/hip_bf16.h>

// MLA forward, round 12:
//  - attention: 128 q-rows/block again (8 waves x 16 rows, proven spill-free
//    per-wave code from r9/r11), single-buffered 44 KB LDS, launch_bounds(512,4)
//    -> 2 blocks/CU (16 waves/CU). stage -> bar -> compute -> bar.
//  - V' stored TILE-BLOCKED: vp2[b,h][t/32][c][t%32] so each V-tile stage is
//    one contiguous 8 KB read (r11 read 128 scattered 64B chunks -> L2 thrash).
//  - XCD-chunked swizzle: xcd=flat&7 -> (batch, 4-head group); per-XCD L2
//    working set = 1 batch kvn (2MB) + 4 vpT slices (2MB) ~ 4MB L2.
//  - r10/r11 kept: V'-folded PV, in-register P transpose, Ootomo kv-proj,
//    m97-style GEMMs, s_setprio around MFMA clusters.
// B=2 S=2048 D=2048 H=16 NOPE=128 ROPE=64 V=128 C=512
#define B_ 2
#define S_ 2048
#define H_ 16

typedef unsigned short ushort_t;
typedef unsigned int uint_t;
typedef __attribute__((ext_vector_type(8))) short bf16x8;
typedef __attribute__((ext_vector_type(4))) float f32x4;

__device__ __forceinline__ ushort_t f2bf(float f) {
    uint_t u = __float_as_uint(f);
    return (ushort_t)((u + 0x7fffu + ((u >> 16) & 1u)) >> 16);
}
__device__ __forceinline__ float bf2f(ushort_t v) {
    return __uint_as_float(((uint_t)v) << 16);
}

// global -> LDS direct copy, 16B per lane. LDS dest wave-uniform; HW writes
// lane i at ldsbase + i*16. Global src per-lane.
__device__ __forceinline__ void gl_lds16(const ushort_t* g, ushort_t* l) {
    __builtin_amdgcn_global_load_lds(
        (const __attribute__((address_space(1))) unsigned int*)(unsigned long long)g,
        (__attribute__((address_space(3))) unsigned int*)(unsigned int)(unsigned long long)l,
        16, 0, 0);
}

// ---------------------------------------------------------------------------
// f32 -> bf16 cast
// ---------------------------------------------------------------------------
__global__ __launch_bounds__(256) void cast_bf16(const float* __restrict__ src,
                                                 ushort_t* __restrict__ dst, int n)
{
    int i = (blockIdx.x * 256 + threadIdx.x) * 4;
    if (i < n) {
        float4 v = *(const float4*)(src + i);
        ushort_t pk[4] = { f2bf(v.x), f2bf(v.y), f2bf(v.z), f2bf(v.w) };
        *(uint2*)(dst + i) = *(const uint2*)pk;
    }
}

// f32 -> bf16 hi + bf16 lo (residual) split cast
__global__ __launch_bounds__(256) void cast2_bf16(const float* __restrict__ src,
                                                  ushort_t* __restrict__ hi,
                                                  ushort_t* __restrict__ lo, int n)
{
    int i = (blockIdx.x * 256 + threadIdx.x) * 4;
    if (i < n) {
        float4 v = *(const float4*)(src + i);
        float vv[4] = { v.x, v.y, v.z, v.w };
        ushort_t ph[4], pl[4];
#pragma unroll
        for (int k = 0; k < 4; k++) {
            ph[k] = f2bf(vv[k]);
            pl[k] = f2bf(vv[k] - bf2f(ph[k]));
        }
        *(uint2*)(hi + i) = *(const uint2*)ph;
        *(uint2*)(lo + i) = *(const uint2*)pl;
    }
}

// ---------------------------------------------------------------------------
// bf16 MFMA GEMM (m97-style): C[M,N] = A[M,K] @ B[N,K]^T. M%128==0, N%128==0
// (tiling), K%64==0. Nreal guards B-row reads and C stores; ldc = C stride.
// mode: 0 = f32 store, 1 = bf16 store, 2 = f32 accumulate.
// ---------------------------------------------------------------------------
__global__ __launch_bounds__(256, 2) void gemm_bf16(const ushort_t* __restrict__ A,
                                                    const ushort_t* __restrict__ Bm,
                                                    float* __restrict__ Cf,
                                                    ushort_t* __restrict__ Cb,
                                                    int M, int N, int K,
                                                    int ldc, int Nreal, int mode)
{
    __shared__ __align__(16) ushort_t As[2][8192];
    __shared__ __align__(16) ushort_t Bs[2][8192];
    const int tid = threadIdx.x;
    const int wv = tid >> 6, lane = tid & 63, l16 = lane & 15, quad = lane >> 4;
    const int wm = wv >> 1, wn = wv & 1;
    const int m0 = blockIdx.y * 128, n0 = blockIdx.x * 128;
    const int srow = lane >> 3;                  // 0..7 within 8-row chunk
    const int sch  = ((lane & 7) ^ srow) * 8;    // swizzled source chunk (ushorts)

    f32x4 acc[16];
#pragma unroll
    for (int i = 0; i < 16; i++) acc[i] = (f32x4)(0.f);

    // prologue: stage k0=0 into buf 0
#pragma unroll
    for (int p = 0; p < 4; p++) {
        int g = wv + p*4, row = g*8 + srow;
        int rowb = n0 + row; if (rowb > Nreal - 1) rowb = Nreal - 1;
        gl_lds16(A  + (size_t)(m0 + row) * K + sch, &As[0][g*512]);
        gl_lds16(Bm + (size_t)rowb * K + sch,       &Bs[0][g*512]);
    }
    __syncthreads();

    int cur = 0;
    for (int k0 = 0; k0 < K; k0 += 64) {
        if (k0 + 64 < K) {
#pragma unroll
            for (int p = 0; p < 4; p++) {
                int g = wv + p*4, row = g*8 + srow;
                int rowb = n0 + row; if (rowb > Nreal - 1) rowb = Nreal - 1;
                gl_lds16(A  + (size_t)(m0 + row) * K + k0 + 64 + sch, &As[cur^1][g*512]);
                gl_lds16(Bm + (size_t)rowb * K + k0 + 64 + sch,       &Bs[cur^1][g*512]);
            }
        }
#pragma unroll
        for (int ks = 0; ks < 2; ks++) {
            bf16x8 af[4], bfr[4];
#pragma unroll
            for (int mt = 0; mt < 4; mt++) {
                int row = wm*64 + mt*16 + l16;
                af[mt] = *(const bf16x8*)(&As[cur][row*64 + (((ks*4+quad) ^ (l16&7))*8)]);
            }
#pragma unroll
            for (int nt = 0; nt < 4; nt++) {
                int row = wn*64 + nt*16 + l16;
                bfr[nt] = *(const bf16x8*)(&Bs[cur][row*64 + (((ks*4+quad) ^ (l16&7))*8)]);
            }
#pragma unroll
            for (int mt = 0; mt < 4; mt++)
#pragma unroll
                for (int nt = 0; nt < 4; nt++)
                    acc[mt*4+nt] = __builtin_amdgcn_mfma_f32_16x16x32_bf16(af[mt], bfr[nt], acc[mt*4+nt], 0, 0, 0);
        }
        __syncthreads();
        cur ^= 1;
    }
#pragma unroll
    for (int mt = 0; mt < 4; mt++)
#pragma unroll
        for (int nt = 0; nt < 4; nt++) {
            int cc = n0 + wn*64 + nt*16 + l16;
            if (cc < Nreal) {
#pragma unroll
                for (int r = 0; r < 4; r++) {
                    size_t rr = m0 + wm*64 + mt*16 + quad*4 + r;
                    float v = acc[mt*4+nt][r];
                    if (mode == 1)      Cb[rr*ldc + cc] = f2bf(v);
                    else if (mode == 2) Cf[rr*ldc + cc] += v;
                    else                Cf[rr*ldc + cc] = v;
                }
            }
        }
}

// ---------------------------------------------------------------------------
// V' GEMM: vp2[b,h][t/32][c][t%32] = sum_k kvn[b,t,k] * wbv[h,c,k].
// Tile 128x128, K=512; tile-blocked output layout for contiguous attn stages.
// ---------------------------------------------------------------------------
__global__ __launch_bounds__(256, 2) void gemm_vp(const ushort_t* __restrict__ kvnb,
                                                  const ushort_t* __restrict__ wbvB,
                                                  ushort_t* __restrict__ vp2)
{
    __shared__ __align__(16) ushort_t As[2][8192];
    __shared__ __align__(16) ushort_t Bs[2][8192];
    const int tid = threadIdx.x;
    const int wv = tid >> 6, lane = tid & 63, l16 = lane & 15, quad = lane >> 4;
    const int wm = wv >> 1, wn = wv & 1;
    const int m0 = blockIdx.x * 128;
    const int h  = blockIdx.y;
    const ushort_t* Bh = wbvB + h*65536;
    const int srow = lane >> 3;
    const int sch  = ((lane & 7) ^ srow) * 8;

    f32x4 acc[16];
#pragma unroll
    for (int i = 0; i < 16; i++) acc[i] = (f32x4)(0.f);

#pragma unroll
    for (int p = 0; p < 4; p++) {
        int g = wv + p*4, row = g*8 + srow;
        gl_lds16(kvnb + (size_t)(m0 + row)*512 + sch, &As[0][g*512]);
        gl_lds16(Bh   + (size_t)row*512 + sch,        &Bs[0][g*512]);
    }
    __syncthreads();

    int cur = 0;
    for (int k0 = 0; k0 < 512; k0 += 64) {
        if (k0 + 64 < 512) {
#pragma unroll
            for (int p = 0; p < 4; p++) {
                int g = wv + p*4, row = g*8 + srow;
                gl_lds16(kvnb + (size_t)(m0 + row)*512 + k0 + 64 + sch, &As[cur^1][g*512]);
                gl_lds16(Bh   + (size_t)row*512 + k0 + 64 + sch,        &Bs[cur^1][g*512]);
            }
        }
#pragma unroll
        for (int ks = 0; ks < 2; ks++) {
            bf16x8 af[4], bfr[4];
#pragma unroll
            for (int mt = 0; mt < 4; mt++) {
                int row = wm*64 + mt*16 + l16;
                af[mt] = *(const bf16x8*)(&As[cur][row*64 + (((ks*4+quad) ^ (l16&7))*8)]);
            }
#pragma unroll
            for (int nt = 0; nt < 4; nt++) {
                int row = wn*64 + nt*16 + l16;
                bfr[nt] = *(const bf16x8*)(&Bs[cur][row*64 + (((ks*4+quad) ^ (l16&7))*8)]);
            }
#pragma unroll
            for (int mt = 0; mt < 4; mt++)
#pragma unroll
                for (int nt = 0; nt < 4; nt++)
                    acc[mt*4+nt] = __builtin_amdgcn_mfma_f32_16x16x32_bf16(af[mt], bfr[nt], acc[mt*4+nt], 0, 0, 0);
        }
        __syncthreads();
        cur ^= 1;
    }
    // scatter: 4 consecutive t per lane -> uint2 into tile-blocked layout
#pragma unroll
    for (int mt = 0; mt < 4; mt++)
#pragma unroll
        for (int nt = 0; nt < 4; nt++) {
            int rr = m0 + wm*64 + mt*16 + quad*4;   // global t (4 consecutive)
            int bb = rr >> 11, t = rr & 2047;
            int cc = wn*64 + nt*16 + l16;            // c
            ushort_t pk[4];
#pragma unroll
            for (int r = 0; r < 4; r++) pk[r] = f2bf(acc[mt*4+nt][r]);
            *(uint2*)(vp2 + ((size_t)((bb*16 + h)*64 + (t >> 5)))*4096 + cc*32 + (t & 31))
                = *(const uint2*)pk;
        }
}

// ---------------------------------------------------------------------------
__global__ __launch_bounds__(256) void prep_wb(const float* __restrict__ wkv_b,
                                               ushort_t* __restrict__ wbkT,
                                               ushort_t* __restrict__ wbvB)
{
    int u = blockIdx.x * 256 + threadIdx.x;
    {
        int h = u >> 16, rem = u & 65535, c = rem >> 7, d = rem & 127;
        wbkT[u] = f2bf(wkv_b[h*131072 + d*512 + c]);
    }
    {
        int h = u >> 16, rem = u & 65535;
        wbvB[u] = f2bf(wkv_b[h*131072 + 65536 + rem]);
    }
}

// ---------------------------------------------------------------------------
__global__ __launch_bounds__(256) void kv_norm_rope(const float* __restrict__ kvr,
                                                    const float* __restrict__ w,
                                                    const float* __restrict__ cosT,
                                                    const float* __restrict__ sinT,
                                                    ushort_t* __restrict__ kvnb,
                                                    ushort_t* __restrict__ kpeb)
{
    const int bs   = blockIdx.x * 4 + (threadIdx.x >> 6);
    const int lane = threadIdx.x & 63;
    const int s    = bs & (S_ - 1);
    const float* row = kvr + bs * 576;

    float4 v0 = *(const float4*)(row + lane*8);
    float4 v1 = *(const float4*)(row + lane*8 + 4);
    float ss = v0.x*v0.x + v0.y*v0.y + v0.z*v0.z + v0.w*v0.w
             + v1.x*v1.x + v1.y*v1.y + v1.z*v1.z + v1.w*v1.w;
#pragma unroll
    for (int off = 32; off >= 1; off >>= 1) ss += __shfl_xor(ss, off);
    const float rs = rsqrtf(ss * (1.0f/512.0f) + 1e-6f);

    float4 w0 = *(const float4*)(w + lane*8);
    float4 w1 = *(const float4*)(w + lane*8 + 4);
    float o[8];
    o[0] = v0.x*rs*w0.x; o[1] = v0.y*rs*w0.y; o[2] = v0.z*rs*w0.z; o[3] = v0.w*rs*w0.w;
    o[4] = v1.x*rs*w1.x; o[5] = v1.y*rs*w1.y; o[6] = v1.z*rs*w1.z; o[7] = v1.w*rs*w1.w;

    ushort_t pk[8];
#pragma unroll
    for (int p = 0; p < 8; p++) pk[p] = f2bf(o[p]);
    *(uint4*)(kvnb + (size_t)bs*512 + lane*8) = *(const uint4*)pk;

    if (lane < 32) {
        float xr = row[512 + 2*lane], xi = row[512 + 2*lane + 1];
        float c  = cosT[s*32 + lane], sn = sinT[s*32 + lane];
        ushort_t p2[2] = { f2bf(xr*c - xi*sn), f2bf(xr*sn + xi*c) };
        *(uint_t*)(kpeb + (size_t)bs*64 + 2*lane) = *(const uint_t*)p2;
    }
}

// ---------------------------------------------------------------------------
// MFMA flash attention v10: 8 waves x 16 q-rows (128/block), 16x16x32 MFMA,
// single-buffered 44 KB LDS -> 2 blocks/CU (16 waves/CU), tile-blocked V',
// in-register P transpose, XCD-chunked swizzle.
// ---------------------------------------------------------------------------
__global__ __launch_bounds__(512, 4) void attn_mfma(
    const ushort_t* __restrict__ qb,
    const ushort_t* __restrict__ kvnb,
    const ushort_t* __restrict__ kpeb,
    const ushort_t* __restrict__ vp2,
    const float* __restrict__ cosT,
    const float* __restrict__ sinT,
    const ushort_t* __restrict__ wbkT,
    ushort_t* __restrict__ ovb)
{
    // XCD-chunked swizzle (blockIdx -> XCD assumed round-robin %8):
    // xcd 0..3 -> batch 0 heads 4*xcd.., xcd 4..7 -> batch 1. Per-XCD L2 then
    // holds 1 batch kvn (2MB) + 4 vpT slices (2MB). LPT q-order within chunk.
    const int flat = blockIdx.x;
    const int xcd  = flat & 7;
    const int j    = flat >> 3;          // 0..63
    const int b    = xcd >> 2;
    const int h    = (xcd & 3) * 4 + (j >> 4);
    const int q0   = (15 - (j & 15)) << 7;

    const int tid  = threadIdx.x;
    const int w    = tid >> 6;       // 0..7
    const int lane = tid & 63;
    const int l16  = lane & 15;
    const int quad = lane >> 4;
    const int tl   = quad * 4;
    const int lb   = lane & 48;
    const int q8e  = quad * 8;
    const float scale = 0.07216878364870323f;   // 192^-0.5

    // LDS (ushorts): F = 0..18431 (36 groups x 512), V = 18432..22527 (8 x 512).
    // Phase-A scratch overlays F (w*2176, 8 waves = 34816 B < 36864), dead by loop.
    __shared__ __align__(16) ushort_t lds[22528];   // 45056 B
    ushort_t* F = lds;
    ushort_t* V = lds + 18432;

    const ushort_t* kvn_b = kvnb + (size_t)b*S_*512;
    const ushort_t* kpe_b = kpeb + (size_t)b*S_*64;
    const ushort_t* vp2_h = vp2 + (size_t)(b*16 + h)*64*4096;

    const int r0    = q0 + w*16;
    const int rglob = r0 + l16;

    // ===== phase A: q_abs*scale as B-frags qf[0..15], pe -> qf[16..17]
    ushort_t* paw = lds + w*2176;
    const ushort_t* qrow = qb + (size_t)(b*S_ + rglob)*3072 + h*192;
    bf16x8 qa[4], qf[18];
#pragma unroll
    for (int ks = 0; ks < 4; ks++)
        qa[ks] = *(const bf16x8*)(qrow + ks*32 + q8e);

    const ushort_t* wbk_h = wbkT + h*65536;
#pragma unroll
    for (int qq = 0; qq < 4; qq++) {
        f32x4 ab[8];
#pragma unroll
        for (int n = 0; n < 8; n++) ab[n] = (f32x4)(0.f);
#pragma unroll
        for (int n = 0; n < 8; n++) {
            const ushort_t* wp = wbk_h + (qq*128 + n*16 + l16)*128 + q8e;
#pragma unroll
            for (int ks = 0; ks < 4; ks++) {
                bf16x8 bw = *(const bf16x8*)(wp + ks*32);
                ab[n] = __builtin_amdgcn_mfma_f32_16x16x32_bf16(qa[ks], bw, ab[n], 0, 0, 0);
            }
        }
        asm volatile("" ::: "memory");
#pragma unroll
        for (int n = 0; n < 8; n++)
#pragma unroll
            for (int r = 0; r < 4; r++)
                paw[(tl + r)*136 + n*16 + l16] = f2bf(ab[n][r] * scale);
        asm volatile("" ::: "memory");
#pragma unroll
        for (int ks2 = 0; ks2 < 4; ks2++)
            qf[qq*4 + ks2] = *(const bf16x8*)(paw + l16*136 + ks2*32 + q8e);
        asm volatile("" ::: "memory");
    }

#pragma unroll
    for (int kk = 0; kk < 2; kk++) {
        int off = kk*32 + q8e;
        uint4 pv4 = *(const uint4*)(qrow + 128 + off);
        const ushort_t* pe = (const ushort_t*)&pv4;
        ushort_t pk[8];
#pragma unroll
        for (int u2 = 0; u2 < 4; u2++) {
            float xr = bf2f(pe[2*u2]), xi = bf2f(pe[2*u2+1]);
            int pi = (off >> 1) + u2;
            float c = cosT[rglob*32 + pi], sn = sinT[rglob*32 + pi];
            pk[2*u2]   = f2bf((xr*c  - xi*sn) * scale);
            pk[2*u2+1] = f2bf((xr*sn + xi*c ) * scale);
        }
        qf[16 + kk] = *(const bf16x8*)pk;
    }
    __syncthreads();   // phase-A scratch dead before first stage

    // ===== flash main loop: TK=32, single buffer, stage->bar->compute->bar =====
    f32x4 o[8];
#pragma unroll
    for (int n = 0; n < 8; n++) o[n] = (f32x4)(0.f);
    float m_s = -1e30f, l_s = 0.f;

    const int bniter = (q0 >> 5) + 4;            // block-uniform tile count
    const int wniter = ((r0 + 15) >> 5) + 1;     // this wave's causal bound

#pragma unroll 1
    for (int it = 0; it < bniter; it++) {
        const int t0 = it * 32;
        // stage: 4-5 F groups + 1 V group per wave (w-strided over 8 waves)
#pragma unroll
        for (int ii = 0; ii < 5; ii++) {
            int g = w + ii*8;
            if (g < 36) {
                int g2 = (g >= 18) ? 1 : 0;
                int ks = g - g2*18;
                int row = t0 + g2*16 + l16;
                const ushort_t* src = (ks < 16)
                    ? (kvn_b + (size_t)row*512 + ks*32 + q8e)
                    : (kpe_b + (size_t)row*64 + (ks-16)*32 + q8e);
                gl_lds16(src, F + g*512);
            }
        }
        {
            // V group w: contiguous 1KB slice of the 8KB tile-blocked V' tile
            const ushort_t* src = vp2_h + (size_t)(t0 >> 5)*4096 + (w*16 + l16)*32 + q8e;
            gl_lds16(src, V + w*512);
        }
        __syncthreads();   // staging drained + visible

        if (it < wniter) {
            __builtin_amdgcn_s_setprio(1);
            // S^T: C col = q-row (l16), C row = key (tl+reg); two 16-key groups
            f32x4 s0 = (f32x4)(0.f), s1 = (f32x4)(0.f);
#pragma unroll
            for (int ks = 0; ks < 18; ks++) {
                bf16x8 kf0 = *(const bf16x8*)(F + ks*512 + lane*8);
                s0 = __builtin_amdgcn_mfma_f32_16x16x32_bf16(kf0, qf[ks], s0, 0, 0, 0);
                bf16x8 kf1 = *(const bf16x8*)(F + 9216 + ks*512 + lane*8);
                s1 = __builtin_amdgcn_mfma_f32_16x16x32_bf16(kf1, qf[ks], s1, 0, 0, 0);
            }
            __builtin_amdgcn_s_setprio(0);

            // online softmax for q-row rglob
            float pv[8];
            float mx = -1e30f;
#pragma unroll
            for (int reg = 0; reg < 4; reg++) {
                pv[reg]   = ((t0 + tl + reg)      <= rglob) ? s0[reg] : -1e30f;
                pv[4+reg] = ((t0 + 16 + tl + reg) <= rglob) ? s1[reg] : -1e30f;
                mx = fmaxf(mx, fmaxf(pv[reg], pv[4+reg]));
            }
            mx = fmaxf(mx, __shfl_xor(mx, 16));
            mx = fmaxf(mx, __shfl_xor(mx, 32));
            if (!__all(mx <= m_s)) {        // exact skip when max unchanged
                float mn = fmaxf(m_s, mx);
                float al = __expf(m_s - mn);
                m_s = mn;
                l_s *= al;
                f32x4 alv;
#pragma unroll
                for (int reg = 0; reg < 4; reg++) alv[reg] = __shfl(al, lb + tl + reg, 64);
#pragma unroll
                for (int n = 0; n < 8; n++) o[n] *= alv;
            }
            float ps = 0.f;
#pragma unroll
            for (int reg = 0; reg < 8; reg++) {
                pv[reg] = (pv[reg] > -1e29f) ? __expf(pv[reg] - m_s) : 0.f;
                ps += pv[reg];
            }
            ps += __shfl_xor(ps, 16);
            ps += __shfl_xor(ps, 32);
            l_s += ps;

            // P^T -> A-frag fully in-register: 8 shfl + 4 selects.
            uint_t p00 = (uint_t)f2bf(pv[0]) | ((uint_t)f2bf(pv[1]) << 16);
            uint_t p01 = (uint_t)f2bf(pv[2]) | ((uint_t)f2bf(pv[3]) << 16);
            uint_t p10 = (uint_t)f2bf(pv[4]) | ((uint_t)f2bf(pv[5]) << 16);
            uint_t p11 = (uint_t)f2bf(pv[6]) | ((uint_t)f2bf(pv[7]) << 16);
            int Sa = l16 + ((lane & 16) << 1);   // l16 + 32*(quad&1)
            int Sb = Sa + 16;
            uint_t xa0 = (uint_t)__shfl((int)p00, Sa, 64);
            uint_t xa1 = (uint_t)__shfl((int)p01, Sa, 64);
            uint_t ya0 = (uint_t)__shfl((int)p10, Sa, 64);
            uint_t ya1 = (uint_t)__shfl((int)p11, Sa, 64);
            uint_t xb0 = (uint_t)__shfl((int)p00, Sb, 64);
            uint_t xb1 = (uint_t)__shfl((int)p01, Sb, 64);
            uint_t yb0 = (uint_t)__shfl((int)p10, Sb, 64);
            uint_t yb1 = (uint_t)__shfl((int)p11, Sb, 64);
            bool g1 = quad >= 2;
            uint4 aw;
            aw.x = g1 ? ya0 : xa0;
            aw.y = g1 ? ya1 : xa1;
            aw.z = g1 ? yb0 : xb0;
            aw.w = g1 ? yb1 : xb1;
            bf16x8 ap = *(const bf16x8*)&aw;

            // PV': o[n] += P[r][t] * V'[t][c], c = n*16 + l16
            __builtin_amdgcn_s_setprio(1);
#pragma unroll
            for (int n = 0; n < 8; n++) {
                bf16x8 bv = *(const bf16x8*)(V + n*512 + lane*8);
                o[n] = __builtin_amdgcn_mfma_f32_16x16x32_bf16(ap, bv, o[n], 0, 0, 0);
            }
            __builtin_amdgcn_s_setprio(0);
        }
        __syncthreads();   // reads done before next stage overwrites
    }

    // ===== output: ovb = o / l =====
    float linv = 1.f / l_s;
    f32x4 rlv;
#pragma unroll
    for (int reg = 0; reg < 4; reg++) rlv[reg] = __shfl(linv, lb + tl + reg, 64);

    ushort_t* orow = ovb + (size_t)(b*S_ + r0)*2048 + h*128;
#pragma unroll
    for (int n = 0; n < 8; n++)
#pragma unroll
        for (int reg = 0; reg < 4; reg++)
            orow[(size_t)(tl + reg)*2048 + n*16 + l16] = f2bf(o[n][reg] * rlv[reg]);
}

// ---------------------------------------------------------------------------
extern "C" void kernel_launch(void* const* d_in, const int* in_sizes, int n_in,
                              void* d_out, int out_size, void* d_ws, size_t ws_size,
                              hipStream_t stream) {
    const float* x     = (const float*)d_in[0];
    const float* cosT  = (const float*)d_in[1];
    const float* sinT  = (const float*)d_in[2];
    // d_in[3] mask: unused (causality applied directly)
    const float* wq    = (const float*)d_in[4];
    const float* wkv_a = (const float*)d_in[5];
    const float* kvw   = (const float*)d_in[6];
    const float* wkv_b = (const float*)d_in[7];
    const float* wo    = (const float*)d_in[8];
    float* out = (float*)d_out;

    ushort_t* qb   = (ushort_t*)d_ws;       // 4096x3072 bf16
    ushort_t* xb   = qb   + 12582912;       // 4096x2048 x-hi; later vp2
    ushort_t* wqb  = xb   + 8388608;        // 3072x2048; later wa_hi/wa_lo
    ushort_t* wob  = wqb  + 6291456;        // 2048x2048
    ushort_t* ovb  = wob  + 4194304;        // x-lo early; attn output later
    ushort_t* kvnb = ovb  + 8388608;        // 4096x512
    ushort_t* kpeb = kvnb + 2097152;        // 4096x64
    ushort_t* kvnT = kpeb + 262144;         // unused slot
    ushort_t* wbkT = kvnT + 2097152;        // 16x512x128
    ushort_t* wbvB = wbkT + 1048576;        // 16x128x512
    float*    kvr  = (float*)(wbvB + 1048576);  // 4096x576 f32

    ushort_t* xlo  = ovb;                   // 4096x2048 bf16 (dead until attn)
    ushort_t* wahi = wqb;                   // 576x2048 bf16 (after q-proj)
    ushort_t* walo = wqb + 1179648;         // 576x2048 bf16
    ushort_t* vp2  = xb;                    // 2x16x64x4096 bf16 (after kv gemms)

    dim3 blk(256);
    cast2_bf16<<<dim3(8192), blk, 0, stream>>>(x, xb, xlo, 8388608);
    cast_bf16<<<dim3(6144), blk, 0, stream>>>(wq, wqb, 6291456);
    cast_bf16<<<dim3(4096), blk, 0, stream>>>(wo, wob, 4194304);
    prep_wb<<<dim3(4096), blk, 0, stream>>>(wkv_b, wbkT, wbvB);
    gemm_bf16<<<dim3(24, 32), blk, 0, stream>>>(xb, wqb, nullptr, qb, 4096, 3072, 2048, 3072, 3072, 1);
    cast2_bf16<<<dim3(1152), blk, 0, stream>>>(wkv_a, wahi, walo, 1179648);
    gemm_bf16<<<dim3(5, 32), blk, 0, stream>>>(xb,  wahi, kvr, nullptr, 4096, 640, 2048, 576, 576, 0);
    gemm_bf16<<<dim3(5, 32), blk, 0, stream>>>(xlo, wahi, kvr, nullptr, 4096, 640, 2048, 576, 576, 2);
    gemm_bf16<<<dim3(5, 32), blk, 0, stream>>>(xb,  walo, kvr, nullptr, 4096, 640, 2048, 576, 576, 2);
    kv_norm_rope<<<dim3(1024), blk, 0, stream>>>(kvr, kvw, cosT, sinT, kvnb, kpeb);
    gemm_vp<<<dim3(32, 16), blk, 0, stream>>>(kvnb, wbvB, vp2);
    attn_mfma<<<dim3(512), dim3(512), 0, stream>>>(qb, kvnb, kpeb, vp2, cosT, sinT, wbkT, ovb);
    gemm_bf16<<<dim3(16, 32), blk, 0, stream>>>(ovb, wob, out, nullptr, 4096, 2048, 2048, 2048, 2048, 0);
}

// Round 7
// 583.593 us; speedup vs baseline: 1.7761x; 1.7761x over previous
//
#include <hip/hip_runtime.h>
#include <hip/hip_bf16.h>

// MLA forward, round 13: best-of-both revert.
//  - attention: VERBATIM round-9 kernel (measured 219 us, FETCH 44 MB, VGPR 88,
//    no spill): 8 waves x 16 q-rows, 16x16x32 MFMA, double-buffered 100 KB LDS,
//    tile-0 prefetch under phase A, LDS P-transpose, flat&1 batch swizzle + LPT.
//  - host pipeline: round-10 version (measured rest ~342 us): Ootomo 3-pass
//    bf16 kv-projection (no f32 VALU GEMM), V'-folded PV via gemm_vp, m97-style
//    gemm_bf16 with mode/Nreal.
// B=2 S=2048 D=2048 H=16 NOPE=128 ROPE=64 V=128 C=512
#define B_ 2
#define S_ 2048
#define H_ 16

typedef unsigned short ushort_t;
typedef unsigned int uint_t;
typedef __attribute__((ext_vector_type(8))) short bf16x8;
typedef __attribute__((ext_vector_type(4))) float f32x4;

__device__ __forceinline__ ushort_t f2bf(float f) {
    uint_t u = __float_as_uint(f);
    return (ushort_t)((u + 0x7fffu + ((u >> 16) & 1u)) >> 16);
}
__device__ __forceinline__ float bf2f(ushort_t v) {
    return __uint_as_float(((uint_t)v) << 16);
}

// global -> LDS direct copy, 16B per lane. LDS dest wave-uniform; HW writes
// lane i at ldsbase + i*16. Global src per-lane.
__device__ __forceinline__ void gl_lds16(const ushort_t* g, ushort_t* l) {
    __builtin_amdgcn_global_load_lds(
        (const __attribute__((address_space(1))) unsigned int*)(unsigned long long)g,
        (__attribute__((address_space(3))) unsigned int*)(unsigned int)(unsigned long long)l,
        16, 0, 0);
}

// ---------------------------------------------------------------------------
// f32 -> bf16 cast
// ---------------------------------------------------------------------------
__global__ __launch_bounds__(256) void cast_bf16(const float* __restrict__ src,
                                                 ushort_t* __restrict__ dst, int n)
{
    int i = (blockIdx.x * 256 + threadIdx.x) * 4;
    if (i < n) {
        float4 v = *(const float4*)(src + i);
        ushort_t pk[4] = { f2bf(v.x), f2bf(v.y), f2bf(v.z), f2bf(v.w) };
        *(uint2*)(dst + i) = *(const uint2*)pk;
    }
}

// f32 -> bf16 hi + bf16 lo (residual) split cast
__global__ __launch_bounds__(256) void cast2_bf16(const float* __restrict__ src,
                                                  ushort_t* __restrict__ hi,
                                                  ushort_t* __restrict__ lo, int n)
{
    int i = (blockIdx.x * 256 + threadIdx.x) * 4;
    if (i < n) {
        float4 v = *(const float4*)(src + i);
        float vv[4] = { v.x, v.y, v.z, v.w };
        ushort_t ph[4], pl[4];
#pragma unroll
        for (int k = 0; k < 4; k++) {
            ph[k] = f2bf(vv[k]);
            pl[k] = f2bf(vv[k] - bf2f(ph[k]));
        }
        *(uint2*)(hi + i) = *(const uint2*)ph;
        *(uint2*)(lo + i) = *(const uint2*)pl;
    }
}

// ---------------------------------------------------------------------------
// bf16 MFMA GEMM (m97-style): C[M,N] = A[M,K] @ B[N,K]^T. M%128==0, N%128==0
// (tiling), K%64==0. Nreal guards B-row reads and C stores; ldc = C stride.
// mode: 0 = f32 store, 1 = bf16 store, 2 = f32 accumulate.
// ---------------------------------------------------------------------------
__global__ __launch_bounds__(256, 2) void gemm_bf16(const ushort_t* __restrict__ A,
                                                    const ushort_t* __restrict__ Bm,
                                                    float* __restrict__ Cf,
                                                    ushort_t* __restrict__ Cb,
                                                    int M, int N, int K,
                                                    int ldc, int Nreal, int mode)
{
    __shared__ __align__(16) ushort_t As[2][8192];
    __shared__ __align__(16) ushort_t Bs[2][8192];
    const int tid = threadIdx.x;
    const int wv = tid >> 6, lane = tid & 63, l16 = lane & 15, quad = lane >> 4;
    const int wm = wv >> 1, wn = wv & 1;
    const int m0 = blockIdx.y * 128, n0 = blockIdx.x * 128;
    const int srow = lane >> 3;                  // 0..7 within 8-row chunk
    const int sch  = ((lane & 7) ^ srow) * 8;    // swizzled source chunk (ushorts)

    f32x4 acc[16];
#pragma unroll
    for (int i = 0; i < 16; i++) acc[i] = (f32x4)(0.f);

    // prologue: stage k0=0 into buf 0
#pragma unroll
    for (int p = 0; p < 4; p++) {
        int g = wv + p*4, row = g*8 + srow;
        int rowb = n0 + row; if (rowb > Nreal - 1) rowb = Nreal - 1;
        gl_lds16(A  + (size_t)(m0 + row) * K + sch, &As[0][g*512]);
        gl_lds16(Bm + (size_t)rowb * K + sch,       &Bs[0][g*512]);
    }
    __syncthreads();

    int cur = 0;
    for (int k0 = 0; k0 < K; k0 += 64) {
        if (k0 + 64 < K) {
#pragma unroll
            for (int p = 0; p < 4; p++) {
                int g = wv + p*4, row = g*8 + srow;
                int rowb = n0 + row; if (rowb > Nreal - 1) rowb = Nreal - 1;
                gl_lds16(A  + (size_t)(m0 + row) * K + k0 + 64 + sch, &As[cur^1][g*512]);
                gl_lds16(Bm + (size_t)rowb * K + k0 + 64 + sch,       &Bs[cur^1][g*512]);
            }
        }
#pragma unroll
        for (int ks = 0; ks < 2; ks++) {
            bf16x8 af[4], bfr[4];
#pragma unroll
            for (int mt = 0; mt < 4; mt++) {
                int row = wm*64 + mt*16 + l16;
                af[mt] = *(const bf16x8*)(&As[cur][row*64 + (((ks*4+quad) ^ (l16&7))*8)]);
            }
#pragma unroll
            for (int nt = 0; nt < 4; nt++) {
                int row = wn*64 + nt*16 + l16;
                bfr[nt] = *(const bf16x8*)(&Bs[cur][row*64 + (((ks*4+quad) ^ (l16&7))*8)]);
            }
#pragma unroll
            for (int mt = 0; mt < 4; mt++)
#pragma unroll
                for (int nt = 0; nt < 4; nt++)
                    acc[mt*4+nt] = __builtin_amdgcn_mfma_f32_16x16x32_bf16(af[mt], bfr[nt], acc[mt*4+nt], 0, 0, 0);
        }
        __syncthreads();
        cur ^= 1;
    }
#pragma unroll
    for (int mt = 0; mt < 4; mt++)
#pragma unroll
        for (int nt = 0; nt < 4; nt++) {
            int cc = n0 + wn*64 + nt*16 + l16;
            if (cc < Nreal) {
#pragma unroll
                for (int r = 0; r < 4; r++) {
                    size_t rr = m0 + wm*64 + mt*16 + quad*4 + r;
                    float v = acc[mt*4+nt][r];
                    if (mode == 1)      Cb[rr*ldc + cc] = f2bf(v);
                    else if (mode == 2) Cf[rr*ldc + cc] += v;
                    else                Cf[rr*ldc + cc] = v;
                }
            }
        }
}

// ---------------------------------------------------------------------------
// V' GEMM: vpT[b][h][c][t] = sum_k kvn[b,t,k] * wbv[h,c,k]. Tile 128x128, K=512.
// ---------------------------------------------------------------------------
__global__ __launch_bounds__(256, 2) void gemm_vp(const ushort_t* __restrict__ kvnb,
                                                  const ushort_t* __restrict__ wbvB,
                                                  ushort_t* __restrict__ vpT)
{
    __shared__ __align__(16) ushort_t As[2][8192];
    __shared__ __align__(16) ushort_t Bs[2][8192];
    const int tid = threadIdx.x;
    const int wv = tid >> 6, lane = tid & 63, l16 = lane & 15, quad = lane >> 4;
    const int wm = wv >> 1, wn = wv & 1;
    const int m0 = blockIdx.x * 128;
    const int h  = blockIdx.y;
    const ushort_t* Bh = wbvB + h*65536;
    const int srow = lane >> 3;
    const int sch  = ((lane & 7) ^ srow) * 8;

    f32x4 acc[16];
#pragma unroll
    for (int i = 0; i < 16; i++) acc[i] = (f32x4)(0.f);

#pragma unroll
    for (int p = 0; p < 4; p++) {
        int g = wv + p*4, row = g*8 + srow;
        gl_lds16(kvnb + (size_t)(m0 + row)*512 + sch, &As[0][g*512]);
        gl_lds16(Bh   + (size_t)row*512 + sch,        &Bs[0][g*512]);
    }
    __syncthreads();

    int cur = 0;
    for (int k0 = 0; k0 < 512; k0 += 64) {
        if (k0 + 64 < 512) {
#pragma unroll
            for (int p = 0; p < 4; p++) {
                int g = wv + p*4, row = g*8 + srow;
                gl_lds16(kvnb + (size_t)(m0 + row)*512 + k0 + 64 + sch, &As[cur^1][g*512]);
                gl_lds16(Bh   + (size_t)row*512 + k0 + 64 + sch,        &Bs[cur^1][g*512]);
            }
        }
#pragma unroll
        for (int ks = 0; ks < 2; ks++) {
            bf16x8 af[4], bfr[4];
#pragma unroll
            for (int mt = 0; mt < 4; mt++) {
                int row = wm*64 + mt*16 + l16;
                af[mt] = *(const bf16x8*)(&As[cur][row*64 + (((ks*4+quad) ^ (l16&7))*8)]);
            }
#pragma unroll
            for (int nt = 0; nt < 4; nt++) {
                int row = wn*64 + nt*16 + l16;
                bfr[nt] = *(const bf16x8*)(&Bs[cur][row*64 + (((ks*4+quad) ^ (l16&7))*8)]);
            }
#pragma unroll
            for (int mt = 0; mt < 4; mt++)
#pragma unroll
                for (int nt = 0; nt < 4; nt++)
                    acc[mt*4+nt] = __builtin_amdgcn_mfma_f32_16x16x32_bf16(af[mt], bfr[nt], acc[mt*4+nt], 0, 0, 0);
        }
        __syncthreads();
        cur ^= 1;
    }
    // scatter: 4 consecutive t per lane -> uint2
#pragma unroll
    for (int mt = 0; mt < 4; mt++)
#pragma unroll
        for (int nt = 0; nt < 4; nt++) {
            int rr = m0 + wm*64 + mt*16 + quad*4;
            int bb = rr >> 11, t = rr & 2047;
            int cc = wn*64 + nt*16 + l16;
            ushort_t pk[4];
#pragma unroll
            for (int r = 0; r < 4; r++) pk[r] = f2bf(acc[mt*4+nt][r]);
            *(uint2*)(vpT + ((size_t)((bb*16 + h)*128 + cc))*2048 + t) = *(const uint2*)pk;
        }
}

// ---------------------------------------------------------------------------
__global__ __launch_bounds__(256) void prep_wb(const float* __restrict__ wkv_b,
                                               ushort_t* __restrict__ wbkT,
                                               ushort_t* __restrict__ wbvB)
{
    int u = blockIdx.x * 256 + threadIdx.x;
    {
        int h = u >> 16, rem = u & 65535, c = rem >> 7, d = rem & 127;
        wbkT[u] = f2bf(wkv_b[h*131072 + d*512 + c]);
    }
    {
        int h = u >> 16, rem = u & 65535;
        wbvB[u] = f2bf(wkv_b[h*131072 + 65536 + rem]);
    }
}

// ---------------------------------------------------------------------------
__global__ __launch_bounds__(256) void kv_norm_rope(const float* __restrict__ kvr,
                                                    const float* __restrict__ w,
                                                    const float* __restrict__ cosT,
                                                    const float* __restrict__ sinT,
                                                    ushort_t* __restrict__ kvnb,
                                                    ushort_t* __restrict__ kpeb)
{
    const int bs   = blockIdx.x * 4 + (threadIdx.x >> 6);
    const int lane = threadIdx.x & 63;
    const int s    = bs & (S_ - 1);
    const float* row = kvr + bs * 576;

    float4 v0 = *(const float4*)(row + lane*8);
    float4 v1 = *(const float4*)(row + lane*8 + 4);
    float ss = v0.x*v0.x + v0.y*v0.y + v0.z*v0.z + v0.w*v0.w
             + v1.x*v1.x + v1.y*v1.y + v1.z*v1.z + v1.w*v1.w;
#pragma unroll
    for (int off = 32; off >= 1; off >>= 1) ss += __shfl_xor(ss, off);
    const float rs = rsqrtf(ss * (1.0f/512.0f) + 1e-6f);

    float4 w0 = *(const float4*)(w + lane*8);
    float4 w1 = *(const float4*)(w + lane*8 + 4);
    float o[8];
    o[0] = v0.x*rs*w0.x; o[1] = v0.y*rs*w0.y; o[2] = v0.z*rs*w0.z; o[3] = v0.w*rs*w0.w;
    o[4] = v1.x*rs*w1.x; o[5] = v1.y*rs*w1.y; o[6] = v1.z*rs*w1.z; o[7] = v1.w*rs*w1.w;

    ushort_t pk[8];
#pragma unroll
    for (int p = 0; p < 8; p++) pk[p] = f2bf(o[p]);
    *(uint4*)(kvnb + (size_t)bs*512 + lane*8) = *(const uint4*)pk;

    if (lane < 32) {
        float xr = row[512 + 2*lane], xi = row[512 + 2*lane + 1];
        float c  = cosT[s*32 + lane], sn = sinT[s*32 + lane];
        ushort_t p2[2] = { f2bf(xr*c - xi*sn), f2bf(xr*sn + xi*c) };
        *(uint_t*)(kpeb + (size_t)bs*64 + 2*lane) = *(const uint_t*)p2;
    }
}

// ---------------------------------------------------------------------------
// stage one 32-key tile: K (36 frag-groups) -> F[buf], V' (8 groups) -> vt[buf]
// lane-linear frag layout; wave w issues its subset.
// ---------------------------------------------------------------------------
__device__ __forceinline__ void stage_tile(const ushort_t* kvn_b, const ushort_t* kpe_b,
                                           const ushort_t* vpT_h, ushort_t* ldsb,
                                           int t0, int buf, int w, int l16, int q8e)
{
    ushort_t* Fb = ldsb + buf*18432;
    ushort_t* Vb = ldsb + 36864 + buf*4096;
#pragma unroll
    for (int ii = 0; ii < 5; ii++) {
        int i = w + ii*8;
        if (i < 36) {
            int g2 = (i >= 18) ? 1 : 0;
            int ks = i - g2*18;
            int row = t0 + g2*16 + l16;
            const ushort_t* src = (ks < 16)
                ? (kvn_b + (size_t)row*512 + ks*32 + q8e)
                : (kpe_b + (size_t)row*64 + (ks-16)*32 + q8e);
            gl_lds16(src, Fb + i*512);
        }
    }
    {
        const ushort_t* src = vpT_h + (size_t)(w*16 + l16)*2048 + t0 + q8e;
        gl_lds16(src, Vb + w*512);
    }
}

// ---------------------------------------------------------------------------
// MFMA flash attention (verbatim round-9, measured 219 us): 128 q-rows/block,
// 8 waves x 16 unique rows, TK=32, V'-folded PV (o[8]), double-buffered LDS,
// 1 barrier/tile.
// ---------------------------------------------------------------------------
__global__ __launch_bounds__(512, 2) void attn_mfma(
    const ushort_t* __restrict__ qb,
    const ushort_t* __restrict__ kvnb,
    const ushort_t* __restrict__ kpeb,
    const ushort_t* __restrict__ vpT,
    const float* __restrict__ cosT,
    const float* __restrict__ sinT,
    const ushort_t* __restrict__ wbkT,
    ushort_t* __restrict__ ovb)
{
    // XCD/LPT swizzle: batch = flat&1, longest causal blocks first
    const int flat = blockIdx.x + 16*blockIdx.y + 256*blockIdx.z;
    const int b    = flat & 1;
    const int rem  = flat >> 1;
    const int h    = rem & 15;
    const int q0   = (15 - (rem >> 4)) << 7;

    const int tid  = threadIdx.x;
    const int w    = tid >> 6;
    const int lane = tid & 63;
    const int l16  = lane & 15;
    const int quad = lane >> 4;
    const int tl   = quad * 4;
    const int lb   = lane & 48;
    const int q8e  = quad * 8;
    const float scale = 0.07216878364870323f;   // 192^-0.5

    // LDS map (ushort elems): F[0]=0, F[1]=18432 (36KB x2); vt[buf]=36864+buf*4096
    // (8KB x2); pt = 45056 + w*640; phase-A scr overlay = 18432 + w*2176 (in F[1])
    __shared__ __align__(16) ushort_t lds[50176];   // 100352 B

    const ushort_t* kvn_b = kvnb + (size_t)b*S_*512;
    const ushort_t* kpe_b = kpeb + (size_t)b*S_*64;
    const ushort_t* vpT_h = vpT + (size_t)(b*16 + h)*128*2048;

    const int r0    = q0 + w*16;
    const int rglob = r0 + l16;

    // ---- prologue: stage tile 0 into buf 0 (hides under phase A)
    stage_tile(kvn_b, kpe_b, vpT_h, lds, 0, 0, w, l16, q8e);

    // ===== phase A: q_abs*scale as B-frags qf[0..15], pe -> qf[16..17]
    ushort_t* paw = lds + 18432 + w*2176;
    const ushort_t* qrow = qb + (size_t)(b*S_ + rglob)*3072 + h*192;
    bf16x8 qa[4], qf[18];
#pragma unroll
    for (int ks = 0; ks < 4; ks++)
        qa[ks] = *(const bf16x8*)(qrow + ks*32 + q8e);

    const ushort_t* wbk_h = wbkT + h*65536;
#pragma unroll
    for (int qq = 0; qq < 4; qq++) {
        f32x4 ab[8];
#pragma unroll
        for (int n = 0; n < 8; n++) ab[n] = (f32x4)(0.f);
#pragma unroll
        for (int n = 0; n < 8; n++) {
            const ushort_t* wp = wbk_h + (qq*128 + n*16 + l16)*128 + q8e;
#pragma unroll
            for (int ks = 0; ks < 4; ks++) {
                bf16x8 bw = *(const bf16x8*)(wp + ks*32);
                ab[n] = __builtin_amdgcn_mfma_f32_16x16x32_bf16(qa[ks], bw, ab[n], 0, 0, 0);
            }
        }
        asm volatile("" ::: "memory");
#pragma unroll
        for (int n = 0; n < 8; n++)
#pragma unroll
            for (int r = 0; r < 4; r++)
                paw[(tl + r)*136 + n*16 + l16] = f2bf(ab[n][r] * scale);
        asm volatile("" ::: "memory");
#pragma unroll
        for (int ks2 = 0; ks2 < 4; ks2++)
            qf[qq*4 + ks2] = *(const bf16x8*)(paw + l16*136 + ks2*32 + q8e);
        asm volatile("" ::: "memory");
    }

#pragma unroll
    for (int kk = 0; kk < 2; kk++) {
        int off = kk*32 + q8e;
        uint4 pv4 = *(const uint4*)(qrow + 128 + off);
        const ushort_t* pe = (const ushort_t*)&pv4;
        ushort_t pk[8];
#pragma unroll
        for (int u2 = 0; u2 < 4; u2++) {
            float xr = bf2f(pe[2*u2]), xi = bf2f(pe[2*u2+1]);
            int pi = (off >> 1) + u2;
            float c = cosT[rglob*32 + pi], sn = sinT[rglob*32 + pi];
            pk[2*u2]   = f2bf((xr*c  - xi*sn) * scale);
            pk[2*u2+1] = f2bf((xr*sn + xi*c ) * scale);
        }
        qf[16 + kk] = *(const bf16x8*)pk;
    }
    __syncthreads();   // phase-A LDS done + tile0 staging drained

    // ===== flash main loop: TK=32, double-buffered, 1 barrier/tile =====
    f32x4 o[8];
#pragma unroll
    for (int n = 0; n < 8; n++) o[n] = (f32x4)(0.f);
    float m_s = -1e30f, l_s = 0.f;

    const int bniter = (q0 >> 5) + 4;            // block-uniform tile count
    const int wniter = ((r0 + 15) >> 5) + 1;     // this wave's causal bound
    ushort_t* ptw = lds + 45056 + w*640;
    int cur = 0;

#pragma unroll 1
    for (int it = 0; it < bniter; it++) {
        if (it + 1 < bniter)
            stage_tile(kvn_b, kpe_b, vpT_h, lds, (it+1)*32, cur ^ 1, w, l16, q8e);

        if (it < wniter) {
            const int t0 = it * 32;
            const ushort_t* Fb = lds + cur*18432;
            const ushort_t* Vb = lds + 36864 + cur*4096;

            // S^T: C col = q-row (l16), C row = key (tl+reg); two 16-key groups
            f32x4 s0 = (f32x4)(0.f), s1 = (f32x4)(0.f);
#pragma unroll
            for (int ks = 0; ks < 18; ks++) {
                bf16x8 kf0 = *(const bf16x8*)(Fb + ks*512 + lane*8);
                s0 = __builtin_amdgcn_mfma_f32_16x16x32_bf16(kf0, qf[ks], s0, 0, 0, 0);
                bf16x8 kf1 = *(const bf16x8*)(Fb + 9216 + ks*512 + lane*8);
                s1 = __builtin_amdgcn_mfma_f32_16x16x32_bf16(kf1, qf[ks], s1, 0, 0, 0);
            }

            // online softmax for q-row rglob
            float pv[8];
            float mx = -1e30f;
#pragma unroll
            for (int reg = 0; reg < 4; reg++) {
                pv[reg]   = ((t0 + tl + reg)      <= rglob) ? s0[reg] : -1e30f;
                pv[4+reg] = ((t0 + 16 + tl + reg) <= rglob) ? s1[reg] : -1e30f;
                mx = fmaxf(mx, fmaxf(pv[reg], pv[4+reg]));
            }
            mx = fmaxf(mx, __shfl_xor(mx, 16));
            mx = fmaxf(mx, __shfl_xor(mx, 32));
            if (!__all(mx <= m_s)) {        // exact skip when max unchanged
                float mn = fmaxf(m_s, mx);
                float al = __expf(m_s - mn);
                m_s = mn;
                l_s *= al;
                f32x4 alv;
#pragma unroll
                for (int reg = 0; reg < 4; reg++) alv[reg] = __shfl(al, lb + tl + reg, 64);
#pragma unroll
                for (int n = 0; n < 8; n++) o[n] *= alv;
            }
            float ps = 0.f;
#pragma unroll
            for (int reg = 0; reg < 8; reg++) {
                pv[reg] = (pv[reg] > -1e29f) ? __expf(pv[reg] - m_s) : 0.f;
                ps += pv[reg];
            }
            ps += __shfl_xor(ps, 16);
            ps += __shfl_xor(ps, 32);
            l_s += ps;

            // P^T -> ptw (per-wave), fence, read back A-frag (k=32)
            ushort_t pk4[8];
#pragma unroll
            for (int reg = 0; reg < 8; reg++) pk4[reg] = f2bf(pv[reg]);
            *(uint2*)(ptw + l16*40 + tl)      = *(const uint2*)(pk4);
            *(uint2*)(ptw + l16*40 + 16 + tl) = *(const uint2*)(pk4 + 4);
            asm volatile("" ::: "memory");
            bf16x8 ap = *(const bf16x8*)(ptw + l16*40 + q8e);
            asm volatile("" ::: "memory");

            // PV': o[n] += P[r][t] * V'[t][c], c = n*16 + l16 (128-dim output)
#pragma unroll
            for (int n = 0; n < 8; n++) {
                bf16x8 bv = *(const bf16x8*)(Vb + n*512 + lane*8);
                o[n] = __builtin_amdgcn_mfma_f32_16x16x32_bf16(ap, bv, o[n], 0, 0, 0);
            }
        }
        __syncthreads();   // next-tile staging drained + cur-buffer reads done
        cur ^= 1;
    }

    // ===== output: ovb = o / l (no epilogue GEMM) =====
    float linv = 1.f / l_s;
    f32x4 rlv;
#pragma unroll
    for (int reg = 0; reg < 4; reg++) rlv[reg] = __shfl(linv, lb + tl + reg, 64);

    ushort_t* orow = ovb + (size_t)(b*S_ + r0)*2048 + h*128;
#pragma unroll
    for (int n = 0; n < 8; n++)
#pragma unroll
        for (int reg = 0; reg < 4; reg++)
            orow[(size_t)(tl + reg)*2048 + n*16 + l16] = f2bf(o[n][reg] * rlv[reg]);
}

// ---------------------------------------------------------------------------
extern "C" void kernel_launch(void* const* d_in, const int* in_sizes, int n_in,
                              void* d_out, int out_size, void* d_ws, size_t ws_size,
                              hipStream_t stream) {
    const float* x     = (const float*)d_in[0];
    const float* cosT  = (const float*)d_in[1];
    const float* sinT  = (const float*)d_in[2];
    // d_in[3] mask: unused (causality applied directly)
    const float* wq    = (const float*)d_in[4];
    const float* wkv_a = (const float*)d_in[5];
    const float* kvw   = (const float*)d_in[6];
    const float* wkv_b = (const float*)d_in[7];
    const float* wo    = (const float*)d_in[8];
    float* out = (float*)d_out;

    ushort_t* qb   = (ushort_t*)d_ws;       // 4096x3072 bf16
    ushort_t* xb   = qb   + 12582912;       // 4096x2048 x-hi; later vpT
    ushort_t* wqb  = xb   + 8388608;        // 3072x2048; later wa_hi/wa_lo
    ushort_t* wob  = wqb  + 6291456;        // 2048x2048
    ushort_t* ovb  = wob  + 4194304;        // x-lo early; attn output later
    ushort_t* kvnb = ovb  + 8388608;        // 4096x512
    ushort_t* kpeb = kvnb + 2097152;        // 4096x64
    ushort_t* kvnT = kpeb + 262144;         // unused slot
    ushort_t* wbkT = kvnT + 2097152;        // 16x512x128
    ushort_t* wbvB = wbkT + 1048576;        // 16x128x512
    float*    kvr  = (float*)(wbvB + 1048576);  // 4096x576 f32

    ushort_t* xlo  = ovb;                   // 4096x2048 bf16 (dead until attn)
    ushort_t* wahi = wqb;                   // 576x2048 bf16 (after q-proj)
    ushort_t* walo = wqb + 1179648;         // 576x2048 bf16
    ushort_t* vpT  = xb;                    // 2x16x128x2048 bf16 (after kv gemms)

    dim3 blk(256);
    cast2_bf16<<<dim3(8192), blk, 0, stream>>>(x, xb, xlo, 8388608);
    cast_bf16<<<dim3(6144), blk, 0, stream>>>(wq, wqb, 6291456);
    cast_bf16<<<dim3(4096), blk, 0, stream>>>(wo, wob, 4194304);
    prep_wb<<<dim3(4096), blk, 0, stream>>>(wkv_b, wbkT, wbvB);
    gemm_bf16<<<dim3(24, 32), blk, 0, stream>>>(xb, wqb, nullptr, qb, 4096, 3072, 2048, 3072, 3072, 1);
    cast2_bf16<<<dim3(1152), blk, 0, stream>>>(wkv_a, wahi, walo, 1179648);
    gemm_bf16<<<dim3(5, 32), blk, 0, stream>>>(xb,  wahi, kvr, nullptr, 4096, 640, 2048, 576, 576, 0);
    gemm_bf16<<<dim3(5, 32), blk, 0, stream>>>(xlo, wahi, kvr, nullptr, 4096, 640, 2048, 576, 576, 2);
    gemm_bf16<<<dim3(5, 32), blk, 0, stream>>>(xb,  walo, kvr, nullptr, 4096, 640, 2048, 576, 576, 2);
    kv_norm_rope<<<dim3(1024), blk, 0, stream>>>(kvr, kvw, cosT, sinT, kvnb, kpeb);
    gemm_vp<<<dim3(32, 16), blk, 0, stream>>>(kvnb, wbvB, vpT);
    attn_mfma<<<dim3(16, 16, 2), dim3(512), 0, stream>>>(qb, kvnb, kpeb, vpT, cosT, sinT, wbkT, ovb);
    gemm_bf16<<<dim3(16, 32), blk, 0, stream>>>(ovb, wob, out, nullptr, 4096, 2048, 2048, 2048, 2048, 0);
}

// Round 8
// 573.474 us; speedup vs baseline: 1.8075x; 1.0176x over previous
//
#include <hip/hip_runtime.h>
#include <hip/hip_bf16.h>

// MLA forward, round 14:
//  - attention: r13 structure, LDS cut 100352->81920 B (exactly 80 KB) for
//    2 blocks/CU: pt region removed via r11's in-register P-transpose
//    (8 shfl + 4 selects, verified), V single-buffered with a uniform
//    mid-tile barrier (stage V(t)+F(t+1) -> S^T -> bar -> PV -> bar).
//  - kv-projection: 3 Ootomo passes fused into gemm_kv3 (stage xhi/xlo/whi/wlo
//    once, 3 MFMA chains into one f32 acc, single store) - was 3x160-block
//    latency-naked launches with global f32 accumulate.
//  - rest verbatim r13.
// B=2 S=2048 D=2048 H=16 NOPE=128 ROPE=64 V=128 C=512
#define B_ 2
#define S_ 2048
#define H_ 16

typedef unsigned short ushort_t;
typedef unsigned int uint_t;
typedef __attribute__((ext_vector_type(8))) short bf16x8;
typedef __attribute__((ext_vector_type(4))) float f32x4;

__device__ __forceinline__ ushort_t f2bf(float f) {
    uint_t u = __float_as_uint(f);
    return (ushort_t)((u + 0x7fffu + ((u >> 16) & 1u)) >> 16);
}
__device__ __forceinline__ float bf2f(ushort_t v) {
    return __uint_as_float(((uint_t)v) << 16);
}

// global -> LDS direct copy, 16B per lane. LDS dest wave-uniform; HW writes
// lane i at ldsbase + i*16. Global src per-lane.
__device__ __forceinline__ void gl_lds16(const ushort_t* g, ushort_t* l) {
    __builtin_amdgcn_global_load_lds(
        (const __attribute__((address_space(1))) unsigned int*)(unsigned long long)g,
        (__attribute__((address_space(3))) unsigned int*)(unsigned int)(unsigned long long)l,
        16, 0, 0);
}

// ---------------------------------------------------------------------------
// f32 -> bf16 cast
// ---------------------------------------------------------------------------
__global__ __launch_bounds__(256) void cast_bf16(const float* __restrict__ src,
                                                 ushort_t* __restrict__ dst, int n)
{
    int i = (blockIdx.x * 256 + threadIdx.x) * 4;
    if (i < n) {
        float4 v = *(const float4*)(src + i);
        ushort_t pk[4] = { f2bf(v.x), f2bf(v.y), f2bf(v.z), f2bf(v.w) };
        *(uint2*)(dst + i) = *(const uint2*)pk;
    }
}

// f32 -> bf16 hi + bf16 lo (residual) split cast
__global__ __launch_bounds__(256) void cast2_bf16(const float* __restrict__ src,
                                                  ushort_t* __restrict__ hi,
                                                  ushort_t* __restrict__ lo, int n)
{
    int i = (blockIdx.x * 256 + threadIdx.x) * 4;
    if (i < n) {
        float4 v = *(const float4*)(src + i);
        float vv[4] = { v.x, v.y, v.z, v.w };
        ushort_t ph[4], pl[4];
#pragma unroll
        for (int k = 0; k < 4; k++) {
            ph[k] = f2bf(vv[k]);
            pl[k] = f2bf(vv[k] - bf2f(ph[k]));
        }
        *(uint2*)(hi + i) = *(const uint2*)ph;
        *(uint2*)(lo + i) = *(const uint2*)pl;
    }
}

// ---------------------------------------------------------------------------
// bf16 MFMA GEMM (m97-style): C[M,N] = A[M,K] @ B[N,K]^T. M%128==0, N%128==0
// (tiling), K%64==0. Nreal guards B-row reads and C stores; ldc = C stride.
// mode: 0 = f32 store, 1 = bf16 store, 2 = f32 accumulate.
// ---------------------------------------------------------------------------
__global__ __launch_bounds__(256, 2) void gemm_bf16(const ushort_t* __restrict__ A,
                                                    const ushort_t* __restrict__ Bm,
                                                    float* __restrict__ Cf,
                                                    ushort_t* __restrict__ Cb,
                                                    int M, int N, int K,
                                                    int ldc, int Nreal, int mode)
{
    __shared__ __align__(16) ushort_t As[2][8192];
    __shared__ __align__(16) ushort_t Bs[2][8192];
    const int tid = threadIdx.x;
    const int wv = tid >> 6, lane = tid & 63, l16 = lane & 15, quad = lane >> 4;
    const int wm = wv >> 1, wn = wv & 1;
    const int m0 = blockIdx.y * 128, n0 = blockIdx.x * 128;
    const int srow = lane >> 3;                  // 0..7 within 8-row chunk
    const int sch  = ((lane & 7) ^ srow) * 8;    // swizzled source chunk (ushorts)

    f32x4 acc[16];
#pragma unroll
    for (int i = 0; i < 16; i++) acc[i] = (f32x4)(0.f);

    // prologue: stage k0=0 into buf 0
#pragma unroll
    for (int p = 0; p < 4; p++) {
        int g = wv + p*4, row = g*8 + srow;
        int rowb = n0 + row; if (rowb > Nreal - 1) rowb = Nreal - 1;
        gl_lds16(A  + (size_t)(m0 + row) * K + sch, &As[0][g*512]);
        gl_lds16(Bm + (size_t)rowb * K + sch,       &Bs[0][g*512]);
    }
    __syncthreads();

    int cur = 0;
    for (int k0 = 0; k0 < K; k0 += 64) {
        if (k0 + 64 < K) {
#pragma unroll
            for (int p = 0; p < 4; p++) {
                int g = wv + p*4, row = g*8 + srow;
                int rowb = n0 + row; if (rowb > Nreal - 1) rowb = Nreal - 1;
                gl_lds16(A  + (size_t)(m0 + row) * K + k0 + 64 + sch, &As[cur^1][g*512]);
                gl_lds16(Bm + (size_t)rowb * K + k0 + 64 + sch,       &Bs[cur^1][g*512]);
            }
        }
#pragma unroll
        for (int ks = 0; ks < 2; ks++) {
            bf16x8 af[4], bfr[4];
#pragma unroll
            for (int mt = 0; mt < 4; mt++) {
                int row = wm*64 + mt*16 + l16;
                af[mt] = *(const bf16x8*)(&As[cur][row*64 + (((ks*4+quad) ^ (l16&7))*8)]);
            }
#pragma unroll
            for (int nt = 0; nt < 4; nt++) {
                int row = wn*64 + nt*16 + l16;
                bfr[nt] = *(const bf16x8*)(&Bs[cur][row*64 + (((ks*4+quad) ^ (l16&7))*8)]);
            }
#pragma unroll
            for (int mt = 0; mt < 4; mt++)
#pragma unroll
                for (int nt = 0; nt < 4; nt++)
                    acc[mt*4+nt] = __builtin_amdgcn_mfma_f32_16x16x32_bf16(af[mt], bfr[nt], acc[mt*4+nt], 0, 0, 0);
        }
        __syncthreads();
        cur ^= 1;
    }
#pragma unroll
    for (int mt = 0; mt < 4; mt++)
#pragma unroll
        for (int nt = 0; nt < 4; nt++) {
            int cc = n0 + wn*64 + nt*16 + l16;
            if (cc < Nreal) {
#pragma unroll
                for (int r = 0; r < 4; r++) {
                    size_t rr = m0 + wm*64 + mt*16 + quad*4 + r;
                    float v = acc[mt*4+nt][r];
                    if (mode == 1)      Cb[rr*ldc + cc] = f2bf(v);
                    else if (mode == 2) Cf[rr*ldc + cc] += v;
                    else                Cf[rr*ldc + cc] = v;
                }
            }
        }
}

// ---------------------------------------------------------------------------
// Fused Ootomo kv-projection: C[M,576] = xhi@whi^T + xlo@whi^T + xhi@wlo^T,
// f32 store. Tile 128x128, K=2048, single-buffered 64 KB LDS (2 blocks/CU).
// ---------------------------------------------------------------------------
__global__ __launch_bounds__(256, 2) void gemm_kv3(const ushort_t* __restrict__ Ahg,
                                                   const ushort_t* __restrict__ Alg,
                                                   const ushort_t* __restrict__ Bhg,
                                                   const ushort_t* __restrict__ Blg,
                                                   float* __restrict__ Cf)
{
    __shared__ __align__(16) ushort_t Ah[8192];
    __shared__ __align__(16) ushort_t Al[8192];
    __shared__ __align__(16) ushort_t Bh[8192];
    __shared__ __align__(16) ushort_t Bl[8192];
    const int tid = threadIdx.x;
    const int wv = tid >> 6, lane = tid & 63, l16 = lane & 15, quad = lane >> 4;
    const int wm = wv >> 1, wn = wv & 1;
    const int m0 = blockIdx.y * 128, n0 = blockIdx.x * 128;
    const int srow = lane >> 3;
    const int sch  = ((lane & 7) ^ srow) * 8;
    const int K = 2048;

    f32x4 acc[16];
#pragma unroll
    for (int i = 0; i < 16; i++) acc[i] = (f32x4)(0.f);

    for (int k0 = 0; k0 < K; k0 += 64) {
#pragma unroll
        for (int p = 0; p < 4; p++) {
            int g = wv + p*4, row = g*8 + srow;
            int rowb = n0 + row; if (rowb > 575) rowb = 575;
            gl_lds16(Ahg + (size_t)(m0 + row)*K + k0 + sch, Ah + g*512);
            gl_lds16(Alg + (size_t)(m0 + row)*K + k0 + sch, Al + g*512);
            gl_lds16(Bhg + (size_t)rowb*K + k0 + sch,       Bh + g*512);
            gl_lds16(Blg + (size_t)rowb*K + k0 + sch,       Bl + g*512);
        }
        __syncthreads();
#pragma unroll
        for (int ks = 0; ks < 2; ks++) {
            bf16x8 ah[4], al[4], bh[4], bl[4];
#pragma unroll
            for (int mt = 0; mt < 4; mt++) {
                int off = (wm*64 + mt*16 + l16)*64 + (((ks*4+quad) ^ (l16&7))*8);
                ah[mt] = *(const bf16x8*)(Ah + off);
                al[mt] = *(const bf16x8*)(Al + off);
            }
#pragma unroll
            for (int nt = 0; nt < 4; nt++) {
                int off = (wn*64 + nt*16 + l16)*64 + (((ks*4+quad) ^ (l16&7))*8);
                bh[nt] = *(const bf16x8*)(Bh + off);
                bl[nt] = *(const bf16x8*)(Bl + off);
            }
#pragma unroll
            for (int mt = 0; mt < 4; mt++)
#pragma unroll
                for (int nt = 0; nt < 4; nt++) {
                    acc[mt*4+nt] = __builtin_amdgcn_mfma_f32_16x16x32_bf16(ah[mt], bh[nt], acc[mt*4+nt], 0, 0, 0);
                    acc[mt*4+nt] = __builtin_amdgcn_mfma_f32_16x16x32_bf16(al[mt], bh[nt], acc[mt*4+nt], 0, 0, 0);
                    acc[mt*4+nt] = __builtin_amdgcn_mfma_f32_16x16x32_bf16(ah[mt], bl[nt], acc[mt*4+nt], 0, 0, 0);
                }
        }
        __syncthreads();
    }
#pragma unroll
    for (int mt = 0; mt < 4; mt++)
#pragma unroll
        for (int nt = 0; nt < 4; nt++) {
            int cc = n0 + wn*64 + nt*16 + l16;
            if (cc < 576) {
#pragma unroll
                for (int r = 0; r < 4; r++) {
                    size_t rr = m0 + wm*64 + mt*16 + quad*4 + r;
                    Cf[rr*576 + cc] = acc[mt*4+nt][r];
                }
            }
        }
}

// ---------------------------------------------------------------------------
// V' GEMM: vpT[b][h][c][t] = sum_k kvn[b,t,k] * wbv[h,c,k]. Tile 128x128, K=512.
// ---------------------------------------------------------------------------
__global__ __launch_bounds__(256, 2) void gemm_vp(const ushort_t* __restrict__ kvnb,
                                                  const ushort_t* __restrict__ wbvB,
                                                  ushort_t* __restrict__ vpT)
{
    __shared__ __align__(16) ushort_t As[2][8192];
    __shared__ __align__(16) ushort_t Bs[2][8192];
    const int tid = threadIdx.x;
    const int wv = tid >> 6, lane = tid & 63, l16 = lane & 15, quad = lane >> 4;
    const int wm = wv >> 1, wn = wv & 1;
    const int m0 = blockIdx.x * 128;
    const int h  = blockIdx.y;
    const ushort_t* Bh = wbvB + h*65536;
    const int srow = lane >> 3;
    const int sch  = ((lane & 7) ^ srow) * 8;

    f32x4 acc[16];
#pragma unroll
    for (int i = 0; i < 16; i++) acc[i] = (f32x4)(0.f);

#pragma unroll
    for (int p = 0; p < 4; p++) {
        int g = wv + p*4, row = g*8 + srow;
        gl_lds16(kvnb + (size_t)(m0 + row)*512 + sch, &As[0][g*512]);
        gl_lds16(Bh   + (size_t)row*512 + sch,        &Bs[0][g*512]);
    }
    __syncthreads();

    int cur = 0;
    for (int k0 = 0; k0 < 512; k0 += 64) {
        if (k0 + 64 < 512) {
#pragma unroll
            for (int p = 0; p < 4; p++) {
                int g = wv + p*4, row = g*8 + srow;
                gl_lds16(kvnb + (size_t)(m0 + row)*512 + k0 + 64 + sch, &As[cur^1][g*512]);
                gl_lds16(Bh   + (size_t)row*512 + k0 + 64 + sch,        &Bs[cur^1][g*512]);
            }
        }
#pragma unroll
        for (int ks = 0; ks < 2; ks++) {
            bf16x8 af[4], bfr[4];
#pragma unroll
            for (int mt = 0; mt < 4; mt++) {
                int row = wm*64 + mt*16 + l16;
                af[mt] = *(const bf16x8*)(&As[cur][row*64 + (((ks*4+quad) ^ (l16&7))*8)]);
            }
#pragma unroll
            for (int nt = 0; nt < 4; nt++) {
                int row = wn*64 + nt*16 + l16;
                bfr[nt] = *(const bf16x8*)(&Bs[cur][row*64 + (((ks*4+quad) ^ (l16&7))*8)]);
            }
#pragma unroll
            for (int mt = 0; mt < 4; mt++)
#pragma unroll
                for (int nt = 0; nt < 4; nt++)
                    acc[mt*4+nt] = __builtin_amdgcn_mfma_f32_16x16x32_bf16(af[mt], bfr[nt], acc[mt*4+nt], 0, 0, 0);
        }
        __syncthreads();
        cur ^= 1;
    }
    // scatter: 4 consecutive t per lane -> uint2
#pragma unroll
    for (int mt = 0; mt < 4; mt++)
#pragma unroll
        for (int nt = 0; nt < 4; nt++) {
            int rr = m0 + wm*64 + mt*16 + quad*4;
            int bb = rr >> 11, t = rr & 2047;
            int cc = wn*64 + nt*16 + l16;
            ushort_t pk[4];
#pragma unroll
            for (int r = 0; r < 4; r++) pk[r] = f2bf(acc[mt*4+nt][r]);
            *(uint2*)(vpT + ((size_t)((bb*16 + h)*128 + cc))*2048 + t) = *(const uint2*)pk;
        }
}

// ---------------------------------------------------------------------------
__global__ __launch_bounds__(256) void prep_wb(const float* __restrict__ wkv_b,
                                               ushort_t* __restrict__ wbkT,
                                               ushort_t* __restrict__ wbvB)
{
    int u = blockIdx.x * 256 + threadIdx.x;
    {
        int h = u >> 16, rem = u & 65535, c = rem >> 7, d = rem & 127;
        wbkT[u] = f2bf(wkv_b[h*131072 + d*512 + c]);
    }
    {
        int h = u >> 16, rem = u & 65535;
        wbvB[u] = f2bf(wkv_b[h*131072 + 65536 + rem]);
    }
}

// ---------------------------------------------------------------------------
__global__ __launch_bounds__(256) void kv_norm_rope(const float* __restrict__ kvr,
                                                    const float* __restrict__ w,
                                                    const float* __restrict__ cosT,
                                                    const float* __restrict__ sinT,
                                                    ushort_t* __restrict__ kvnb,
                                                    ushort_t* __restrict__ kpeb)
{
    const int bs   = blockIdx.x * 4 + (threadIdx.x >> 6);
    const int lane = threadIdx.x & 63;
    const int s    = bs & (S_ - 1);
    const float* row = kvr + bs * 576;

    float4 v0 = *(const float4*)(row + lane*8);
    float4 v1 = *(const float4*)(row + lane*8 + 4);
    float ss = v0.x*v0.x + v0.y*v0.y + v0.z*v0.z + v0.w*v0.w
             + v1.x*v1.x + v1.y*v1.y + v1.z*v1.z + v1.w*v1.w;
#pragma unroll
    for (int off = 32; off >= 1; off >>= 1) ss += __shfl_xor(ss, off);
    const float rs = rsqrtf(ss * (1.0f/512.0f) + 1e-6f);

    float4 w0 = *(const float4*)(w + lane*8);
    float4 w1 = *(const float4*)(w + lane*8 + 4);
    float o[8];
    o[0] = v0.x*rs*w0.x; o[1] = v0.y*rs*w0.y; o[2] = v0.z*rs*w0.z; o[3] = v0.w*rs*w0.w;
    o[4] = v1.x*rs*w1.x; o[5] = v1.y*rs*w1.y; o[6] = v1.z*rs*w1.z; o[7] = v1.w*rs*w1.w;

    ushort_t pk[8];
#pragma unroll
    for (int p = 0; p < 8; p++) pk[p] = f2bf(o[p]);
    *(uint4*)(kvnb + (size_t)bs*512 + lane*8) = *(const uint4*)pk;

    if (lane < 32) {
        float xr = row[512 + 2*lane], xi = row[512 + 2*lane + 1];
        float c  = cosT[s*32 + lane], sn = sinT[s*32 + lane];
        ushort_t p2[2] = { f2bf(xr*c - xi*sn), f2bf(xr*sn + xi*c) };
        *(uint_t*)(kpeb + (size_t)bs*64 + 2*lane) = *(const uint_t*)p2;
    }
}

// ---------------------------------------------------------------------------
// stage K-tile (36 frag-groups) into F[buf]; wave w issues its subset.
// ---------------------------------------------------------------------------
__device__ __forceinline__ void stage_F(const ushort_t* kvn_b, const ushort_t* kpe_b,
                                        ushort_t* ldsb, int t0, int buf,
                                        int w, int l16, int q8e)
{
    ushort_t* Fb = ldsb + buf*18432;
#pragma unroll
    for (int ii = 0; ii < 5; ii++) {
        int i = w + ii*8;
        if (i < 36) {
            int g2 = (i >= 18) ? 1 : 0;
            int ks = i - g2*18;
            int row = t0 + g2*16 + l16;
            const ushort_t* src = (ks < 16)
                ? (kvn_b + (size_t)row*512 + ks*32 + q8e)
                : (kpe_b + (size_t)row*64 + (ks-16)*32 + q8e);
            gl_lds16(src, Fb + i*512);
        }
    }
}

// ---------------------------------------------------------------------------
// MFMA flash attention v11: r13 structure at 80 KB LDS -> 2 blocks/CU.
// 128 q-rows/block, 8 waves x 16 rows, TK=32, F double-buffered, V single-
// buffered (mid-tile barrier), in-register P transpose (no pt LDS).
// ---------------------------------------------------------------------------
__global__ __launch_bounds__(512, 2) void attn_mfma(
    const ushort_t* __restrict__ qb,
    const ushort_t* __restrict__ kvnb,
    const ushort_t* __restrict__ kpeb,
    const ushort_t* __restrict__ vpT,
    const float* __restrict__ cosT,
    const float* __restrict__ sinT,
    const ushort_t* __restrict__ wbkT,
    ushort_t* __restrict__ ovb)
{
    // XCD/LPT swizzle: batch = flat&1, longest causal blocks first
    const int flat = blockIdx.x + 16*blockIdx.y + 256*blockIdx.z;
    const int b    = flat & 1;
    const int rem  = flat >> 1;
    const int h    = rem & 15;
    const int q0   = (15 - (rem >> 4)) << 7;

    const int tid  = threadIdx.x;
    const int w    = tid >> 6;
    const int lane = tid & 63;
    const int l16  = lane & 15;
    const int quad = lane >> 4;
    const int tl   = quad * 4;
    const int lb   = lane & 48;
    const int q8e  = quad * 8;
    const float scale = 0.07216878364870323f;   // 192^-0.5

    // LDS map (ushort elems): F[0]=0, F[1]=18432 (36KB x2); V = 36864 (8KB, single)
    // phase-A scr overlay = 18432 + w*2176 (inside F[1], dead before loop)
    __shared__ __align__(16) ushort_t lds[40960];   // 81920 B == 80 KB exactly

    const ushort_t* kvn_b = kvnb + (size_t)b*S_*512;
    const ushort_t* kpe_b = kpeb + (size_t)b*S_*64;
    const ushort_t* vpT_h = vpT + (size_t)(b*16 + h)*128*2048;

    const int r0    = q0 + w*16;
    const int rglob = r0 + l16;

    // ---- prologue: stage F-tile 0 into buf 0 (hides under phase A)
    stage_F(kvn_b, kpe_b, lds, 0, 0, w, l16, q8e);

    // ===== phase A: q_abs*scale as B-frags qf[0..15], pe -> qf[16..17]
    ushort_t* paw = lds + 18432 + w*2176;
    const ushort_t* qrow = qb + (size_t)(b*S_ + rglob)*3072 + h*192;
    bf16x8 qa[4], qf[18];
#pragma unroll
    for (int ks = 0; ks < 4; ks++)
        qa[ks] = *(const bf16x8*)(qrow + ks*32 + q8e);

    const ushort_t* wbk_h = wbkT + h*65536;
#pragma unroll
    for (int qq = 0; qq < 4; qq++) {
        f32x4 ab[8];
#pragma unroll
        for (int n = 0; n < 8; n++) ab[n] = (f32x4)(0.f);
#pragma unroll
        for (int n = 0; n < 8; n++) {
            const ushort_t* wp = wbk_h + (qq*128 + n*16 + l16)*128 + q8e;
#pragma unroll
            for (int ks = 0; ks < 4; ks++) {
                bf16x8 bw = *(const bf16x8*)(wp + ks*32);
                ab[n] = __builtin_amdgcn_mfma_f32_16x16x32_bf16(qa[ks], bw, ab[n], 0, 0, 0);
            }
        }
        asm volatile("" ::: "memory");
#pragma unroll
        for (int n = 0; n < 8; n++)
#pragma unroll
            for (int r = 0; r < 4; r++)
                paw[(tl + r)*136 + n*16 + l16] = f2bf(ab[n][r] * scale);
        asm volatile("" ::: "memory");
#pragma unroll
        for (int ks2 = 0; ks2 < 4; ks2++)
            qf[qq*4 + ks2] = *(const bf16x8*)(paw + l16*136 + ks2*32 + q8e);
        asm volatile("" ::: "memory");
    }

#pragma unroll
    for (int kk = 0; kk < 2; kk++) {
        int off = kk*32 + q8e;
        uint4 pv4 = *(const uint4*)(qrow + 128 + off);
        const ushort_t* pe = (const ushort_t*)&pv4;
        ushort_t pk[8];
#pragma unroll
        for (int u2 = 0; u2 < 4; u2++) {
            float xr = bf2f(pe[2*u2]), xi = bf2f(pe[2*u2+1]);
            int pi = (off >> 1) + u2;
            float c = cosT[rglob*32 + pi], sn = sinT[rglob*32 + pi];
            pk[2*u2]   = f2bf((xr*c  - xi*sn) * scale);
            pk[2*u2+1] = f2bf((xr*sn + xi*c ) * scale);
        }
        qf[16 + kk] = *(const bf16x8*)pk;
    }
    __syncthreads();   // phase-A LDS done + tile0 F staging drained

    // ===== flash main loop: TK=32, F double-buffered, V single, 2 barriers/tile
    f32x4 o[8];
#pragma unroll
    for (int n = 0; n < 8; n++) o[n] = (f32x4)(0.f);
    float m_s = -1e30f, l_s = 0.f;

    const int bniter = (q0 >> 5) + 4;            // block-uniform tile count
    const int wniter = ((r0 + 15) >> 5) + 1;     // this wave's causal bound
    ushort_t* V = lds + 36864;
    int cur = 0;

#pragma unroll 1
    for (int it = 0; it < bniter; it++) {
        const int t0 = it * 32;
        // stage next F-tile (double buffer) + this tile's V (single buffer)
        if (it + 1 < bniter)
            stage_F(kvn_b, kpe_b, lds, t0 + 32, cur ^ 1, w, l16, q8e);
        {
            const ushort_t* src = vpT_h + (size_t)(w*16 + l16)*2048 + t0 + q8e;
            gl_lds16(src, V + w*512);
        }

        bf16x8 ap;
        if (it < wniter) {
            const ushort_t* Fb = lds + cur*18432;

            // S^T: C col = q-row (l16), C row = key (tl+reg); two 16-key groups
            f32x4 s0 = (f32x4)(0.f), s1 = (f32x4)(0.f);
#pragma unroll
            for (int ks = 0; ks < 18; ks++) {
                bf16x8 kf0 = *(const bf16x8*)(Fb + ks*512 + lane*8);
                s0 = __builtin_amdgcn_mfma_f32_16x16x32_bf16(kf0, qf[ks], s0, 0, 0, 0);
                bf16x8 kf1 = *(const bf16x8*)(Fb + 9216 + ks*512 + lane*8);
                s1 = __builtin_amdgcn_mfma_f32_16x16x32_bf16(kf1, qf[ks], s1, 0, 0, 0);
            }

            // online softmax for q-row rglob
            float pv[8];
            float mx = -1e30f;
#pragma unroll
            for (int reg = 0; reg < 4; reg++) {
                pv[reg]   = ((t0 + tl + reg)      <= rglob) ? s0[reg] : -1e30f;
                pv[4+reg] = ((t0 + 16 + tl + reg) <= rglob) ? s1[reg] : -1e30f;
                mx = fmaxf(mx, fmaxf(pv[reg], pv[4+reg]));
            }
            mx = fmaxf(mx, __shfl_xor(mx, 16));
            mx = fmaxf(mx, __shfl_xor(mx, 32));
            if (!__all(mx <= m_s)) {        // exact skip when max unchanged
                float mn = fmaxf(m_s, mx);
                float al = __expf(m_s - mn);
                m_s = mn;
                l_s *= al;
                f32x4 alv;
#pragma unroll
                for (int reg = 0; reg < 4; reg++) alv[reg] = __shfl(al, lb + tl + reg, 64);
#pragma unroll
                for (int n = 0; n < 8; n++) o[n] *= alv;
            }
            float ps = 0.f;
#pragma unroll
            for (int reg = 0; reg < 8; reg++) {
                pv[reg] = (pv[reg] > -1e29f) ? __expf(pv[reg] - m_s) : 0.f;
                ps += pv[reg];
            }
            ps += __shfl_xor(ps, 16);
            ps += __shfl_xor(ps, 32);
            l_s += ps;

            // P^T -> A-frag in-register: 8 shfl + 4 selects (verified r11).
            // src lane (qs,l16) holds pairs of P[q=l16][t=4qs+..]; dest lane
            // (qd,l16) needs t = 8qd..8qd+7.
            uint_t p00 = (uint_t)f2bf(pv[0]) | ((uint_t)f2bf(pv[1]) << 16);
            uint_t p01 = (uint_t)f2bf(pv[2]) | ((uint_t)f2bf(pv[3]) << 16);
            uint_t p10 = (uint_t)f2bf(pv[4]) | ((uint_t)f2bf(pv[5]) << 16);
            uint_t p11 = (uint_t)f2bf(pv[6]) | ((uint_t)f2bf(pv[7]) << 16);
            int Sa = l16 + ((lane & 16) << 1);   // l16 + 32*(quad&1)
            int Sb = Sa + 16;
            uint_t xa0 = (uint_t)__shfl((int)p00, Sa, 64);
            uint_t xa1 = (uint_t)__shfl((int)p01, Sa, 64);
            uint_t ya0 = (uint_t)__shfl((int)p10, Sa, 64);
            uint_t ya1 = (uint_t)__shfl((int)p11, Sa, 64);
            uint_t xb0 = (uint_t)__shfl((int)p00, Sb, 64);
            uint_t xb1 = (uint_t)__shfl((int)p01, Sb, 64);
            uint_t yb0 = (uint_t)__shfl((int)p10, Sb, 64);
            uint_t yb1 = (uint_t)__shfl((int)p11, Sb, 64);
            bool g1 = quad >= 2;
            uint4 aw;
            aw.x = g1 ? ya0 : xa0;
            aw.y = g1 ? ya1 : xa1;
            aw.z = g1 ? yb0 : xb0;
            aw.w = g1 ? yb1 : xb1;
            ap = *(const bf16x8*)&aw;
        }
        __syncthreads();   // V(t) + F(t+1) staging drained & visible (uniform)

        if (it < wniter) {
            // PV': o[n] += P[r][t] * V'[t][c], c = n*16 + l16
#pragma unroll
            for (int n = 0; n < 8; n++) {
                bf16x8 bv = *(const bf16x8*)(V + n*512 + lane*8);
                o[n] = __builtin_amdgcn_mfma_f32_16x16x32_bf16(ap, bv, o[n], 0, 0, 0);
            }
        }
        __syncthreads();   // V reads done before next stage overwrites (uniform)
        cur ^= 1;
    }

    // ===== output: ovb = o / l (no epilogue GEMM) =====
    float linv = 1.f / l_s;
    f32x4 rlv;
#pragma unroll
    for (int reg = 0; reg < 4; reg++) rlv[reg] = __shfl(linv, lb + tl + reg, 64);

    ushort_t* orow = ovb + (size_t)(b*S_ + r0)*2048 + h*128;
#pragma unroll
    for (int n = 0; n < 8; n++)
#pragma unroll
        for (int reg = 0; reg < 4; reg++)
            orow[(size_t)(tl + reg)*2048 + n*16 + l16] = f2bf(o[n][reg] * rlv[reg]);
}

// ---------------------------------------------------------------------------
extern "C" void kernel_launch(void* const* d_in, const int* in_sizes, int n_in,
                              void* d_out, int out_size, void* d_ws, size_t ws_size,
                              hipStream_t stream) {
    const float* x     = (const float*)d_in[0];
    const float* cosT  = (const float*)d_in[1];
    const float* sinT  = (const float*)d_in[2];
    // d_in[3] mask: unused (causality applied directly)
    const float* wq    = (const float*)d_in[4];
    const float* wkv_a = (const float*)d_in[5];
    const float* kvw   = (const float*)d_in[6];
    const float* wkv_b = (const float*)d_in[7];
    const float* wo    = (const float*)d_in[8];
    float* out = (float*)d_out;

    ushort_t* qb   = (ushort_t*)d_ws;       // 4096x3072 bf16
    ushort_t* xb   = qb   + 12582912;       // 4096x2048 x-hi; later vpT
    ushort_t* wqb  = xb   + 8388608;        // 3072x2048; later wa_hi/wa_lo
    ushort_t* wob  = wqb  + 6291456;        // 2048x2048
    ushort_t* ovb  = wob  + 4194304;        // x-lo early; attn output later
    ushort_t* kvnb = ovb  + 8388608;        // 4096x512
    ushort_t* kpeb = kvnb + 2097152;        // 4096x64
    ushort_t* kvnT = kpeb + 262144;         // unused slot
    ushort_t* wbkT = kvnT + 2097152;        // 16x512x128
    ushort_t* wbvB = wbkT + 1048576;        // 16x128x512
    float*    kvr  = (float*)(wbvB + 1048576);  // 4096x576 f32

    ushort_t* xlo  = ovb;                   // 4096x2048 bf16 (dead until attn)
    ushort_t* wahi = wqb;                   // 576x2048 bf16 (after q-proj)
    ushort_t* walo = wqb + 1179648;         // 576x2048 bf16
    ushort_t* vpT  = xb;                    // 2x16x128x2048 bf16 (after kv gemms)

    dim3 blk(256);
    cast2_bf16<<<dim3(8192), blk, 0, stream>>>(x, xb, xlo, 8388608);
    cast_bf16<<<dim3(6144), blk, 0, stream>>>(wq, wqb, 6291456);
    cast_bf16<<<dim3(4096), blk, 0, stream>>>(wo, wob, 4194304);
    prep_wb<<<dim3(4096), blk, 0, stream>>>(wkv_b, wbkT, wbvB);
    gemm_bf16<<<dim3(24, 32), blk, 0, stream>>>(xb, wqb, nullptr, qb, 4096, 3072, 2048, 3072, 3072, 1);
    cast2_bf16<<<dim3(1152), blk, 0, stream>>>(wkv_a, wahi, walo, 1179648);
    gemm_kv3<<<dim3(5, 32), blk, 0, stream>>>(xb, xlo, wahi, walo, kvr);
    kv_norm_rope<<<dim3(1024), blk, 0, stream>>>(kvr, kvw, cosT, sinT, kvnb, kpeb);
    gemm_vp<<<dim3(32, 16), blk, 0, stream>>>(kvnb, wbvB, vpT);
    attn_mfma<<<dim3(16, 16, 2), dim3(512), 0, stream>>>(qb, kvnb, kpeb, vpT, cosT, sinT, wbkT, ovb);
    gemm_bf16<<<dim3(16, 32), blk, 0, stream>>>(ovb, wob, out, nullptr, 4096, 2048, 2048, 2048, 2048, 0);
}

// Round 9
// 533.148 us; speedup vs baseline: 1.9442x; 1.0756x over previous
//
#include <hip/hip_runtime.h>
#include <hip/hip_bf16.h>

// MLA forward, round 15: consolidation.
//  - attention: VERBATIM round-13 kernel (measured 232 us: 8 waves x 16 rows,
//    double-buffered 100 KB LDS, 1 barrier/tile, LDS P-transpose, VGPR 88)
//    + s_setprio(1/0) around S^T and PV MFMA clusters (T5, measured +4-7% on
//    multi-wave attn in isolation).
//  - r14 kept: fused gemm_kv3 Ootomo kv-projection, V'-folded PV via gemm_vp,
//    m97-style gemm_bf16.
//  Lesson from r10/r11/r12/r14: 2-block/CU co-residency for this attn needs
//  total regs <=128/wave (qf[18]=72 + acc ~40 + working ~130-140) - closed.
// B=2 S=2048 D=2048 H=16 NOPE=128 ROPE=64 V=128 C=512
#define B_ 2
#define S_ 2048
#define H_ 16

typedef unsigned short ushort_t;
typedef unsigned int uint_t;
typedef __attribute__((ext_vector_type(8))) short bf16x8;
typedef __attribute__((ext_vector_type(4))) float f32x4;

__device__ __forceinline__ ushort_t f2bf(float f) {
    uint_t u = __float_as_uint(f);
    return (ushort_t)((u + 0x7fffu + ((u >> 16) & 1u)) >> 16);
}
__device__ __forceinline__ float bf2f(ushort_t v) {
    return __uint_as_float(((uint_t)v) << 16);
}

// global -> LDS direct copy, 16B per lane. LDS dest wave-uniform; HW writes
// lane i at ldsbase + i*16. Global src per-lane.
__device__ __forceinline__ void gl_lds16(const ushort_t* g, ushort_t* l) {
    __builtin_amdgcn_global_load_lds(
        (const __attribute__((address_space(1))) unsigned int*)(unsigned long long)g,
        (__attribute__((address_space(3))) unsigned int*)(unsigned int)(unsigned long long)l,
        16, 0, 0);
}

// ---------------------------------------------------------------------------
// f32 -> bf16 cast
// ---------------------------------------------------------------------------
__global__ __launch_bounds__(256) void cast_bf16(const float* __restrict__ src,
                                                 ushort_t* __restrict__ dst, int n)
{
    int i = (blockIdx.x * 256 + threadIdx.x) * 4;
    if (i < n) {
        float4 v = *(const float4*)(src + i);
        ushort_t pk[4] = { f2bf(v.x), f2bf(v.y), f2bf(v.z), f2bf(v.w) };
        *(uint2*)(dst + i) = *(const uint2*)pk;
    }
}

// f32 -> bf16 hi + bf16 lo (residual) split cast
__global__ __launch_bounds__(256) void cast2_bf16(const float* __restrict__ src,
                                                  ushort_t* __restrict__ hi,
                                                  ushort_t* __restrict__ lo, int n)
{
    int i = (blockIdx.x * 256 + threadIdx.x) * 4;
    if (i < n) {
        float4 v = *(const float4*)(src + i);
        float vv[4] = { v.x, v.y, v.z, v.w };
        ushort_t ph[4], pl[4];
#pragma unroll
        for (int k = 0; k < 4; k++) {
            ph[k] = f2bf(vv[k]);
            pl[k] = f2bf(vv[k] - bf2f(ph[k]));
        }
        *(uint2*)(hi + i) = *(const uint2*)ph;
        *(uint2*)(lo + i) = *(const uint2*)pl;
    }
}

// ---------------------------------------------------------------------------
// bf16 MFMA GEMM (m97-style): C[M,N] = A[M,K] @ B[N,K]^T. M%128==0, N%128==0
// (tiling), K%64==0. Nreal guards B-row reads and C stores; ldc = C stride.
// mode: 0 = f32 store, 1 = bf16 store, 2 = f32 accumulate.
// ---------------------------------------------------------------------------
__global__ __launch_bounds__(256, 2) void gemm_bf16(const ushort_t* __restrict__ A,
                                                    const ushort_t* __restrict__ Bm,
                                                    float* __restrict__ Cf,
                                                    ushort_t* __restrict__ Cb,
                                                    int M, int N, int K,
                                                    int ldc, int Nreal, int mode)
{
    __shared__ __align__(16) ushort_t As[2][8192];
    __shared__ __align__(16) ushort_t Bs[2][8192];
    const int tid = threadIdx.x;
    const int wv = tid >> 6, lane = tid & 63, l16 = lane & 15, quad = lane >> 4;
    const int wm = wv >> 1, wn = wv & 1;
    const int m0 = blockIdx.y * 128, n0 = blockIdx.x * 128;
    const int srow = lane >> 3;                  // 0..7 within 8-row chunk
    const int sch  = ((lane & 7) ^ srow) * 8;    // swizzled source chunk (ushorts)

    f32x4 acc[16];
#pragma unroll
    for (int i = 0; i < 16; i++) acc[i] = (f32x4)(0.f);

    // prologue: stage k0=0 into buf 0
#pragma unroll
    for (int p = 0; p < 4; p++) {
        int g = wv + p*4, row = g*8 + srow;
        int rowb = n0 + row; if (rowb > Nreal - 1) rowb = Nreal - 1;
        gl_lds16(A  + (size_t)(m0 + row) * K + sch, &As[0][g*512]);
        gl_lds16(Bm + (size_t)rowb * K + sch,       &Bs[0][g*512]);
    }
    __syncthreads();

    int cur = 0;
    for (int k0 = 0; k0 < K; k0 += 64) {
        if (k0 + 64 < K) {
#pragma unroll
            for (int p = 0; p < 4; p++) {
                int g = wv + p*4, row = g*8 + srow;
                int rowb = n0 + row; if (rowb > Nreal - 1) rowb = Nreal - 1;
                gl_lds16(A  + (size_t)(m0 + row) * K + k0 + 64 + sch, &As[cur^1][g*512]);
                gl_lds16(Bm + (size_t)rowb * K + k0 + 64 + sch,       &Bs[cur^1][g*512]);
            }
        }
#pragma unroll
        for (int ks = 0; ks < 2; ks++) {
            bf16x8 af[4], bfr[4];
#pragma unroll
            for (int mt = 0; mt < 4; mt++) {
                int row = wm*64 + mt*16 + l16;
                af[mt] = *(const bf16x8*)(&As[cur][row*64 + (((ks*4+quad) ^ (l16&7))*8)]);
            }
#pragma unroll
            for (int nt = 0; nt < 4; nt++) {
                int row = wn*64 + nt*16 + l16;
                bfr[nt] = *(const bf16x8*)(&Bs[cur][row*64 + (((ks*4+quad) ^ (l16&7))*8)]);
            }
#pragma unroll
            for (int mt = 0; mt < 4; mt++)
#pragma unroll
                for (int nt = 0; nt < 4; nt++)
                    acc[mt*4+nt] = __builtin_amdgcn_mfma_f32_16x16x32_bf16(af[mt], bfr[nt], acc[mt*4+nt], 0, 0, 0);
        }
        __syncthreads();
        cur ^= 1;
    }
#pragma unroll
    for (int mt = 0; mt < 4; mt++)
#pragma unroll
        for (int nt = 0; nt < 4; nt++) {
            int cc = n0 + wn*64 + nt*16 + l16;
            if (cc < Nreal) {
#pragma unroll
                for (int r = 0; r < 4; r++) {
                    size_t rr = m0 + wm*64 + mt*16 + quad*4 + r;
                    float v = acc[mt*4+nt][r];
                    if (mode == 1)      Cb[rr*ldc + cc] = f2bf(v);
                    else if (mode == 2) Cf[rr*ldc + cc] += v;
                    else                Cf[rr*ldc + cc] = v;
                }
            }
        }
}

// ---------------------------------------------------------------------------
// Fused Ootomo kv-projection: C[M,576] = xhi@whi^T + xlo@whi^T + xhi@wlo^T,
// f32 store. Tile 128x128, K=2048, single-buffered 64 KB LDS (2 blocks/CU).
// ---------------------------------------------------------------------------
__global__ __launch_bounds__(256, 2) void gemm_kv3(const ushort_t* __restrict__ Ahg,
                                                   const ushort_t* __restrict__ Alg,
                                                   const ushort_t* __restrict__ Bhg,
                                                   const ushort_t* __restrict__ Blg,
                                                   float* __restrict__ Cf)
{
    __shared__ __align__(16) ushort_t Ah[8192];
    __shared__ __align__(16) ushort_t Al[8192];
    __shared__ __align__(16) ushort_t Bh[8192];
    __shared__ __align__(16) ushort_t Bl[8192];
    const int tid = threadIdx.x;
    const int wv = tid >> 6, lane = tid & 63, l16 = lane & 15, quad = lane >> 4;
    const int wm = wv >> 1, wn = wv & 1;
    const int m0 = blockIdx.y * 128, n0 = blockIdx.x * 128;
    const int srow = lane >> 3;
    const int sch  = ((lane & 7) ^ srow) * 8;
    const int K = 2048;

    f32x4 acc[16];
#pragma unroll
    for (int i = 0; i < 16; i++) acc[i] = (f32x4)(0.f);

    for (int k0 = 0; k0 < K; k0 += 64) {
#pragma unroll
        for (int p = 0; p < 4; p++) {
            int g = wv + p*4, row = g*8 + srow;
            int rowb = n0 + row; if (rowb > 575) rowb = 575;
            gl_lds16(Ahg + (size_t)(m0 + row)*K + k0 + sch, Ah + g*512);
            gl_lds16(Alg + (size_t)(m0 + row)*K + k0 + sch, Al + g*512);
            gl_lds16(Bhg + (size_t)rowb*K + k0 + sch,       Bh + g*512);
            gl_lds16(Blg + (size_t)rowb*K + k0 + sch,       Bl + g*512);
        }
        __syncthreads();
#pragma unroll
        for (int ks = 0; ks < 2; ks++) {
            bf16x8 ah[4], al[4], bh[4], bl[4];
#pragma unroll
            for (int mt = 0; mt < 4; mt++) {
                int off = (wm*64 + mt*16 + l16)*64 + (((ks*4+quad) ^ (l16&7))*8);
                ah[mt] = *(const bf16x8*)(Ah + off);
                al[mt] = *(const bf16x8*)(Al + off);
            }
#pragma unroll
            for (int nt = 0; nt < 4; nt++) {
                int off = (wn*64 + nt*16 + l16)*64 + (((ks*4+quad) ^ (l16&7))*8);
                bh[nt] = *(const bf16x8*)(Bh + off);
                bl[nt] = *(const bf16x8*)(Bl + off);
            }
#pragma unroll
            for (int mt = 0; mt < 4; mt++)
#pragma unroll
                for (int nt = 0; nt < 4; nt++) {
                    acc[mt*4+nt] = __builtin_amdgcn_mfma_f32_16x16x32_bf16(ah[mt], bh[nt], acc[mt*4+nt], 0, 0, 0);
                    acc[mt*4+nt] = __builtin_amdgcn_mfma_f32_16x16x32_bf16(al[mt], bh[nt], acc[mt*4+nt], 0, 0, 0);
                    acc[mt*4+nt] = __builtin_amdgcn_mfma_f32_16x16x32_bf16(ah[mt], bl[nt], acc[mt*4+nt], 0, 0, 0);
                }
        }
        __syncthreads();
    }
#pragma unroll
    for (int mt = 0; mt < 4; mt++)
#pragma unroll
        for (int nt = 0; nt < 4; nt++) {
            int cc = n0 + wn*64 + nt*16 + l16;
            if (cc < 576) {
#pragma unroll
                for (int r = 0; r < 4; r++) {
                    size_t rr = m0 + wm*64 + mt*16 + quad*4 + r;
                    Cf[rr*576 + cc] = acc[mt*4+nt][r];
                }
            }
        }
}

// ---------------------------------------------------------------------------
// V' GEMM: vpT[b][h][c][t] = sum_k kvn[b,t,k] * wbv[h,c,k]. Tile 128x128, K=512.
// ---------------------------------------------------------------------------
__global__ __launch_bounds__(256, 2) void gemm_vp(const ushort_t* __restrict__ kvnb,
                                                  const ushort_t* __restrict__ wbvB,
                                                  ushort_t* __restrict__ vpT)
{
    __shared__ __align__(16) ushort_t As[2][8192];
    __shared__ __align__(16) ushort_t Bs[2][8192];
    const int tid = threadIdx.x;
    const int wv = tid >> 6, lane = tid & 63, l16 = lane & 15, quad = lane >> 4;
    const int wm = wv >> 1, wn = wv & 1;
    const int m0 = blockIdx.x * 128;
    const int h  = blockIdx.y;
    const ushort_t* Bh = wbvB + h*65536;
    const int srow = lane >> 3;
    const int sch  = ((lane & 7) ^ srow) * 8;

    f32x4 acc[16];
#pragma unroll
    for (int i = 0; i < 16; i++) acc[i] = (f32x4)(0.f);

#pragma unroll
    for (int p = 0; p < 4; p++) {
        int g = wv + p*4, row = g*8 + srow;
        gl_lds16(kvnb + (size_t)(m0 + row)*512 + sch, &As[0][g*512]);
        gl_lds16(Bh   + (size_t)row*512 + sch,        &Bs[0][g*512]);
    }
    __syncthreads();

    int cur = 0;
    for (int k0 = 0; k0 < 512; k0 += 64) {
        if (k0 + 64 < 512) {
#pragma unroll
            for (int p = 0; p < 4; p++) {
                int g = wv + p*4, row = g*8 + srow;
                gl_lds16(kvnb + (size_t)(m0 + row)*512 + k0 + 64 + sch, &As[cur^1][g*512]);
                gl_lds16(Bh   + (size_t)row*512 + k0 + 64 + sch,        &Bs[cur^1][g*512]);
            }
        }
#pragma unroll
        for (int ks = 0; ks < 2; ks++) {
            bf16x8 af[4], bfr[4];
#pragma unroll
            for (int mt = 0; mt < 4; mt++) {
                int row = wm*64 + mt*16 + l16;
                af[mt] = *(const bf16x8*)(&As[cur][row*64 + (((ks*4+quad) ^ (l16&7))*8)]);
            }
#pragma unroll
            for (int nt = 0; nt < 4; nt++) {
                int row = wn*64 + nt*16 + l16;
                bfr[nt] = *(const bf16x8*)(&Bs[cur][row*64 + (((ks*4+quad) ^ (l16&7))*8)]);
            }
#pragma unroll
            for (int mt = 0; mt < 4; mt++)
#pragma unroll
                for (int nt = 0; nt < 4; nt++)
                    acc[mt*4+nt] = __builtin_amdgcn_mfma_f32_16x16x32_bf16(af[mt], bfr[nt], acc[mt*4+nt], 0, 0, 0);
        }
        __syncthreads();
        cur ^= 1;
    }
    // scatter: 4 consecutive t per lane -> uint2
#pragma unroll
    for (int mt = 0; mt < 4; mt++)
#pragma unroll
        for (int nt = 0; nt < 4; nt++) {
            int rr = m0 + wm*64 + mt*16 + quad*4;
            int bb = rr >> 11, t = rr & 2047;
            int cc = wn*64 + nt*16 + l16;
            ushort_t pk[4];
#pragma unroll
            for (int r = 0; r < 4; r++) pk[r] = f2bf(acc[mt*4+nt][r]);
            *(uint2*)(vpT + ((size_t)((bb*16 + h)*128 + cc))*2048 + t) = *(const uint2*)pk;
        }
}

// ---------------------------------------------------------------------------
__global__ __launch_bounds__(256) void prep_wb(const float* __restrict__ wkv_b,
                                               ushort_t* __restrict__ wbkT,
                                               ushort_t* __restrict__ wbvB)
{
    int u = blockIdx.x * 256 + threadIdx.x;
    {
        int h = u >> 16, rem = u & 65535, c = rem >> 7, d = rem & 127;
        wbkT[u] = f2bf(wkv_b[h*131072 + d*512 + c]);
    }
    {
        int h = u >> 16, rem = u & 65535;
        wbvB[u] = f2bf(wkv_b[h*131072 + 65536 + rem]);
    }
}

// ---------------------------------------------------------------------------
__global__ __launch_bounds__(256) void kv_norm_rope(const float* __restrict__ kvr,
                                                    const float* __restrict__ w,
                                                    const float* __restrict__ cosT,
                                                    const float* __restrict__ sinT,
                                                    ushort_t* __restrict__ kvnb,
                                                    ushort_t* __restrict__ kpeb)
{
    const int bs   = blockIdx.x * 4 + (threadIdx.x >> 6);
    const int lane = threadIdx.x & 63;
    const int s    = bs & (S_ - 1);
    const float* row = kvr + bs * 576;

    float4 v0 = *(const float4*)(row + lane*8);
    float4 v1 = *(const float4*)(row + lane*8 + 4);
    float ss = v0.x*v0.x + v0.y*v0.y + v0.z*v0.z + v0.w*v0.w
             + v1.x*v1.x + v1.y*v1.y + v1.z*v1.z + v1.w*v1.w;
#pragma unroll
    for (int off = 32; off >= 1; off >>= 1) ss += __shfl_xor(ss, off);
    const float rs = rsqrtf(ss * (1.0f/512.0f) + 1e-6f);

    float4 w0 = *(const float4*)(w + lane*8);
    float4 w1 = *(const float4*)(w + lane*8 + 4);
    float o[8];
    o[0] = v0.x*rs*w0.x; o[1] = v0.y*rs*w0.y; o[2] = v0.z*rs*w0.z; o[3] = v0.w*rs*w0.w;
    o[4] = v1.x*rs*w1.x; o[5] = v1.y*rs*w1.y; o[6] = v1.z*rs*w1.z; o[7] = v1.w*rs*w1.w;

    ushort_t pk[8];
#pragma unroll
    for (int p = 0; p < 8; p++) pk[p] = f2bf(o[p]);
    *(uint4*)(kvnb + (size_t)bs*512 + lane*8) = *(const uint4*)pk;

    if (lane < 32) {
        float xr = row[512 + 2*lane], xi = row[512 + 2*lane + 1];
        float c  = cosT[s*32 + lane], sn = sinT[s*32 + lane];
        ushort_t p2[2] = { f2bf(xr*c - xi*sn), f2bf(xr*sn + xi*c) };
        *(uint_t*)(kpeb + (size_t)bs*64 + 2*lane) = *(const uint_t*)p2;
    }
}

// ---------------------------------------------------------------------------
// stage one 32-key tile: K (36 frag-groups) -> F[buf], V' (8 groups) -> vt[buf]
// lane-linear frag layout; wave w issues its subset.
// ---------------------------------------------------------------------------
__device__ __forceinline__ void stage_tile(const ushort_t* kvn_b, const ushort_t* kpe_b,
                                           const ushort_t* vpT_h, ushort_t* ldsb,
                                           int t0, int buf, int w, int l16, int q8e)
{
    ushort_t* Fb = ldsb + buf*18432;
    ushort_t* Vb = ldsb + 36864 + buf*4096;
#pragma unroll
    for (int ii = 0; ii < 5; ii++) {
        int i = w + ii*8;
        if (i < 36) {
            int g2 = (i >= 18) ? 1 : 0;
            int ks = i - g2*18;
            int row = t0 + g2*16 + l16;
            const ushort_t* src = (ks < 16)
                ? (kvn_b + (size_t)row*512 + ks*32 + q8e)
                : (kpe_b + (size_t)row*64 + (ks-16)*32 + q8e);
            gl_lds16(src, Fb + i*512);
        }
    }
    {
        const ushort_t* src = vpT_h + (size_t)(w*16 + l16)*2048 + t0 + q8e;
        gl_lds16(src, Vb + w*512);
    }
}

// ---------------------------------------------------------------------------
// MFMA flash attention (round-13 structure, measured 232 us, + setprio):
// 128 q-rows/block, 8 waves x 16 unique rows, TK=32, V'-folded PV (o[8]),
// double-buffered LDS, 1 barrier/tile.
// ---------------------------------------------------------------------------
__global__ __launch_bounds__(512, 2) void attn_mfma(
    const ushort_t* __restrict__ qb,
    const ushort_t* __restrict__ kvnb,
    const ushort_t* __restrict__ kpeb,
    const ushort_t* __restrict__ vpT,
    const float* __restrict__ cosT,
    const float* __restrict__ sinT,
    const ushort_t* __restrict__ wbkT,
    ushort_t* __restrict__ ovb)
{
    // XCD/LPT swizzle: batch = flat&1, longest causal blocks first
    const int flat = blockIdx.x + 16*blockIdx.y + 256*blockIdx.z;
    const int b    = flat & 1;
    const int rem  = flat >> 1;
    const int h    = rem & 15;
    const int q0   = (15 - (rem >> 4)) << 7;

    const int tid  = threadIdx.x;
    const int w    = tid >> 6;
    const int lane = tid & 63;
    const int l16  = lane & 15;
    const int quad = lane >> 4;
    const int tl   = quad * 4;
    const int lb   = lane & 48;
    const int q8e  = quad * 8;
    const float scale = 0.07216878364870323f;   // 192^-0.5

    // LDS map (ushort elems): F[0]=0, F[1]=18432 (36KB x2); vt[buf]=36864+buf*4096
    // (8KB x2); pt = 45056 + w*640; phase-A scr overlay = 18432 + w*2176 (in F[1])
    __shared__ __align__(16) ushort_t lds[50176];   // 100352 B

    const ushort_t* kvn_b = kvnb + (size_t)b*S_*512;
    const ushort_t* kpe_b = kpeb + (size_t)b*S_*64;
    const ushort_t* vpT_h = vpT + (size_t)(b*16 + h)*128*2048;

    const int r0    = q0 + w*16;
    const int rglob = r0 + l16;

    // ---- prologue: stage tile 0 into buf 0 (hides under phase A)
    stage_tile(kvn_b, kpe_b, vpT_h, lds, 0, 0, w, l16, q8e);

    // ===== phase A: q_abs*scale as B-frags qf[0..15], pe -> qf[16..17]
    ushort_t* paw = lds + 18432 + w*2176;
    const ushort_t* qrow = qb + (size_t)(b*S_ + rglob)*3072 + h*192;
    bf16x8 qa[4], qf[18];
#pragma unroll
    for (int ks = 0; ks < 4; ks++)
        qa[ks] = *(const bf16x8*)(qrow + ks*32 + q8e);

    const ushort_t* wbk_h = wbkT + h*65536;
#pragma unroll
    for (int qq = 0; qq < 4; qq++) {
        f32x4 ab[8];
#pragma unroll
        for (int n = 0; n < 8; n++) ab[n] = (f32x4)(0.f);
#pragma unroll
        for (int n = 0; n < 8; n++) {
            const ushort_t* wp = wbk_h + (qq*128 + n*16 + l16)*128 + q8e;
#pragma unroll
            for (int ks = 0; ks < 4; ks++) {
                bf16x8 bw = *(const bf16x8*)(wp + ks*32);
                ab[n] = __builtin_amdgcn_mfma_f32_16x16x32_bf16(qa[ks], bw, ab[n], 0, 0, 0);
            }
        }
        asm volatile("" ::: "memory");
#pragma unroll
        for (int n = 0; n < 8; n++)
#pragma unroll
            for (int r = 0; r < 4; r++)
                paw[(tl + r)*136 + n*16 + l16] = f2bf(ab[n][r] * scale);
        asm volatile("" ::: "memory");
#pragma unroll
        for (int ks2 = 0; ks2 < 4; ks2++)
            qf[qq*4 + ks2] = *(const bf16x8*)(paw + l16*136 + ks2*32 + q8e);
        asm volatile("" ::: "memory");
    }

#pragma unroll
    for (int kk = 0; kk < 2; kk++) {
        int off = kk*32 + q8e;
        uint4 pv4 = *(const uint4*)(qrow + 128 + off);
        const ushort_t* pe = (const ushort_t*)&pv4;
        ushort_t pk[8];
#pragma unroll
        for (int u2 = 0; u2 < 4; u2++) {
            float xr = bf2f(pe[2*u2]), xi = bf2f(pe[2*u2+1]);
            int pi = (off >> 1) + u2;
            float c = cosT[rglob*32 + pi], sn = sinT[rglob*32 + pi];
            pk[2*u2]   = f2bf((xr*c  - xi*sn) * scale);
            pk[2*u2+1] = f2bf((xr*sn + xi*c ) * scale);
        }
        qf[16 + kk] = *(const bf16x8*)pk;
    }
    __syncthreads();   // phase-A LDS done + tile0 staging drained

    // ===== flash main loop: TK=32, double-buffered, 1 barrier/tile =====
    f32x4 o[8];
#pragma unroll
    for (int n = 0; n < 8; n++) o[n] = (f32x4)(0.f);
    float m_s = -1e30f, l_s = 0.f;

    const int bniter = (q0 >> 5) + 4;            // block-uniform tile count
    const int wniter = ((r0 + 15) >> 5) + 1;     // this wave's causal bound
    ushort_t* ptw = lds + 45056 + w*640;
    int cur = 0;

#pragma unroll 1
    for (int it = 0; it < bniter; it++) {
        if (it + 1 < bniter)
            stage_tile(kvn_b, kpe_b, vpT_h, lds, (it+1)*32, cur ^ 1, w, l16, q8e);

        if (it < wniter) {
            const int t0 = it * 32;
            const ushort_t* Fb = lds + cur*18432;
            const ushort_t* Vb = lds + 36864 + cur*4096;

            // S^T: C col = q-row (l16), C row = key (tl+reg); two 16-key groups
            __builtin_amdgcn_s_setprio(1);
            f32x4 s0 = (f32x4)(0.f), s1 = (f32x4)(0.f);
#pragma unroll
            for (int ks = 0; ks < 18; ks++) {
                bf16x8 kf0 = *(const bf16x8*)(Fb + ks*512 + lane*8);
                s0 = __builtin_amdgcn_mfma_f32_16x16x32_bf16(kf0, qf[ks], s0, 0, 0, 0);
                bf16x8 kf1 = *(const bf16x8*)(Fb + 9216 + ks*512 + lane*8);
                s1 = __builtin_amdgcn_mfma_f32_16x16x32_bf16(kf1, qf[ks], s1, 0, 0, 0);
            }
            __builtin_amdgcn_s_setprio(0);

            // online softmax for q-row rglob
            float pv[8];
            float mx = -1e30f;
#pragma unroll
            for (int reg = 0; reg < 4; reg++) {
                pv[reg]   = ((t0 + tl + reg)      <= rglob) ? s0[reg] : -1e30f;
                pv[4+reg] = ((t0 + 16 + tl + reg) <= rglob) ? s1[reg] : -1e30f;
                mx = fmaxf(mx, fmaxf(pv[reg], pv[4+reg]));
            }
            mx = fmaxf(mx, __shfl_xor(mx, 16));
            mx = fmaxf(mx, __shfl_xor(mx, 32));
            if (!__all(mx <= m_s)) {        // exact skip when max unchanged
                float mn = fmaxf(m_s, mx);
                float al = __expf(m_s - mn);
                m_s = mn;
                l_s *= al;
                f32x4 alv;
#pragma unroll
                for (int reg = 0; reg < 4; reg++) alv[reg] = __shfl(al, lb + tl + reg, 64);
#pragma unroll
                for (int n = 0; n < 8; n++) o[n] *= alv;
            }
            float ps = 0.f;
#pragma unroll
            for (int reg = 0; reg < 8; reg++) {
                pv[reg] = (pv[reg] > -1e29f) ? __expf(pv[reg] - m_s) : 0.f;
                ps += pv[reg];
            }
            ps += __shfl_xor(ps, 16);
            ps += __shfl_xor(ps, 32);
            l_s += ps;

            // P^T -> ptw (per-wave), fence, read back A-frag (k=32)
            ushort_t pk4[8];
#pragma unroll
            for (int reg = 0; reg < 8; reg++) pk4[reg] = f2bf(pv[reg]);
            *(uint2*)(ptw + l16*40 + tl)      = *(const uint2*)(pk4);
            *(uint2*)(ptw + l16*40 + 16 + tl) = *(const uint2*)(pk4 + 4);
            asm volatile("" ::: "memory");
            bf16x8 ap = *(const bf16x8*)(ptw + l16*40 + q8e);
            asm volatile("" ::: "memory");

            // PV': o[n] += P[r][t] * V'[t][c], c = n*16 + l16 (128-dim output)
            __builtin_amdgcn_s_setprio(1);
#pragma unroll
            for (int n = 0; n < 8; n++) {
                bf16x8 bv = *(const bf16x8*)(Vb + n*512 + lane*8);
                o[n] = __builtin_amdgcn_mfma_f32_16x16x32_bf16(ap, bv, o[n], 0, 0, 0);
            }
            __builtin_amdgcn_s_setprio(0);
        }
        __syncthreads();   // next-tile staging drained + cur-buffer reads done
        cur ^= 1;
    }

    // ===== output: ovb = o / l (no epilogue GEMM) =====
    float linv = 1.f / l_s;
    f32x4 rlv;
#pragma unroll
    for (int reg = 0; reg < 4; reg++) rlv[reg] = __shfl(linv, lb + tl + reg, 64);

    ushort_t* orow = ovb + (size_t)(b*S_ + r0)*2048 + h*128;
#pragma unroll
    for (int n = 0; n < 8; n++)
#pragma unroll
        for (int reg = 0; reg < 4; reg++)
            orow[(size_t)(tl + reg)*2048 + n*16 + l16] = f2bf(o[n][reg] * rlv[reg]);
}

// ---------------------------------------------------------------------------
extern "C" void kernel_launch(void* const* d_in, const int* in_sizes, int n_in,
                              void* d_out, int out_size, void* d_ws, size_t ws_size,
                              hipStream_t stream) {
    const float* x     = (const float*)d_in[0];
    const float* cosT  = (const float*)d_in[1];
    const float* sinT  = (const float*)d_in[2];
    // d_in[3] mask: unused (causality applied directly)
    const float* wq    = (const float*)d_in[4];
    const float* wkv_a = (const float*)d_in[5];
    const float* kvw   = (const float*)d_in[6];
    const float* wkv_b = (const float*)d_in[7];
    const float* wo    = (const float*)d_in[8];
    float* out = (float*)d_out;

    ushort_t* qb   = (ushort_t*)d_ws;       // 4096x3072 bf16
    ushort_t* xb   = qb   + 12582912;       // 4096x2048 x-hi; later vpT
    ushort_t* wqb  = xb   + 8388608;        // 3072x2048; later wa_hi/wa_lo
    ushort_t* wob  = wqb  + 6291456;        // 2048x2048
    ushort_t* ovb  = wob  + 4194304;        // x-lo early; attn output later
    ushort_t* kvnb = ovb  + 8388608;        // 4096x512
    ushort_t* kpeb = kvnb + 2097152;        // 4096x64
    ushort_t* kvnT = kpeb + 262144;         // unused slot
    ushort_t* wbkT = kvnT + 2097152;        // 16x512x128
    ushort_t* wbvB = wbkT + 1048576;        // 16x128x512
    float*    kvr  = (float*)(wbvB + 1048576);  // 4096x576 f32

    ushort_t* xlo  = ovb;                   // 4096x2048 bf16 (dead until attn)
    ushort_t* wahi = wqb;                   // 576x2048 bf16 (after q-proj)
    ushort_t* walo = wqb + 1179648;         // 576x2048 bf16
    ushort_t* vpT  = xb;                    // 2x16x128x2048 bf16 (after kv gemms)

    dim3 blk(256);
    cast2_bf16<<<dim3(8192), blk, 0, stream>>>(x, xb, xlo, 8388608);
    cast_bf16<<<dim3(6144), blk, 0, stream>>>(wq, wqb, 6291456);
    cast_bf16<<<dim3(4096), blk, 0, stream>>>(wo, wob, 4194304);
    prep_wb<<<dim3(4096), blk, 0, stream>>>(wkv_b, wbkT, wbvB);
    gemm_bf16<<<dim3(24, 32), blk, 0, stream>>>(xb, wqb, nullptr, qb, 4096, 3072, 2048, 3072, 3072, 1);
    cast2_bf16<<<dim3(1152), blk, 0, stream>>>(wkv_a, wahi, walo, 1179648);
    gemm_kv3<<<dim3(5, 32), blk, 0, stream>>>(xb, xlo, wahi, walo, kvr);
    kv_norm_rope<<<dim3(1024), blk, 0, stream>>>(kvr, kvw, cosT, sinT, kvnb, kpeb);
    gemm_vp<<<dim3(32, 16), blk, 0, stream>>>(kvnb, wbvB, vpT);
    attn_mfma<<<dim3(16, 16, 2), dim3(512), 0, stream>>>(qb, kvnb, kpeb, vpT, cosT, sinT, wbkT, ovb);
    gemm_bf16<<<dim3(16, 32), blk, 0, stream>>>(ovb, wob, out, nullptr, 4096, 2048, 2048, 2048, 2048, 0);
}

// Round 10
// 478.878 us; speedup vs baseline: 2.1645x; 1.1133x over previous
//
#include <hip/hip_runtime.h>
#include <hip/hip_bf16.h>

// MLA forward, round 16: K-side absorption.
//  - K' = kvn @ wbk[h]^T precomputed per head (gemm_kp, scale folded in; kpe
//    also pre-scaled). Attention S^T inner dim drops 576->192: 12 S^T MFMAs
//    (was 36), F-tile 12KB (was 36KB), phase A deleted (qf[6] vs qf[18],
//    ~48 VGPRs freed), LDS 51200 B (was 100352).
//  - K' lives in the dead wqb(+wob head) region; wo-cast moved after attn.
//  - r15 kept: setprio, fused gemm_kv3, V'-folded PV, m97 GEMMs, LPT swizzle.
// B=2 S=2048 D=2048 H=16 NOPE=128 ROPE=64 V=128 C=512
#define B_ 2
#define S_ 2048
#define H_ 16

typedef unsigned short ushort_t;
typedef unsigned int uint_t;
typedef __attribute__((ext_vector_type(8))) short bf16x8;
typedef __attribute__((ext_vector_type(4))) float f32x4;

__device__ __forceinline__ ushort_t f2bf(float f) {
    uint_t u = __float_as_uint(f);
    return (ushort_t)((u + 0x7fffu + ((u >> 16) & 1u)) >> 16);
}
__device__ __forceinline__ float bf2f(ushort_t v) {
    return __uint_as_float(((uint_t)v) << 16);
}

// global -> LDS direct copy, 16B per lane. LDS dest wave-uniform; HW writes
// lane i at ldsbase + i*16. Global src per-lane.
__device__ __forceinline__ void gl_lds16(const ushort_t* g, ushort_t* l) {
    __builtin_amdgcn_global_load_lds(
        (const __attribute__((address_space(1))) unsigned int*)(unsigned long long)g,
        (__attribute__((address_space(3))) unsigned int*)(unsigned int)(unsigned long long)l,
        16, 0, 0);
}

// ---------------------------------------------------------------------------
// f32 -> bf16 cast
// ---------------------------------------------------------------------------
__global__ __launch_bounds__(256) void cast_bf16(const float* __restrict__ src,
                                                 ushort_t* __restrict__ dst, int n)
{
    int i = (blockIdx.x * 256 + threadIdx.x) * 4;
    if (i < n) {
        float4 v = *(const float4*)(src + i);
        ushort_t pk[4] = { f2bf(v.x), f2bf(v.y), f2bf(v.z), f2bf(v.w) };
        *(uint2*)(dst + i) = *(const uint2*)pk;
    }
}

// f32 -> bf16 hi + bf16 lo (residual) split cast
__global__ __launch_bounds__(256) void cast2_bf16(const float* __restrict__ src,
                                                  ushort_t* __restrict__ hi,
                                                  ushort_t* __restrict__ lo, int n)
{
    int i = (blockIdx.x * 256 + threadIdx.x) * 4;
    if (i < n) {
        float4 v = *(const float4*)(src + i);
        float vv[4] = { v.x, v.y, v.z, v.w };
        ushort_t ph[4], pl[4];
#pragma unroll
        for (int k = 0; k < 4; k++) {
            ph[k] = f2bf(vv[k]);
            pl[k] = f2bf(vv[k] - bf2f(ph[k]));
        }
        *(uint2*)(hi + i) = *(const uint2*)ph;
        *(uint2*)(lo + i) = *(const uint2*)pl;
    }
}

// ---------------------------------------------------------------------------
// bf16 MFMA GEMM (m97-style): C[M,N] = A[M,K] @ B[N,K]^T. M%128==0, N%128==0
// (tiling), K%64==0. Nreal guards B-row reads and C stores; ldc = C stride.
// mode: 0 = f32 store, 1 = bf16 store, 2 = f32 accumulate.
// ---------------------------------------------------------------------------
__global__ __launch_bounds__(256, 2) void gemm_bf16(const ushort_t* __restrict__ A,
                                                    const ushort_t* __restrict__ Bm,
                                                    float* __restrict__ Cf,
                                                    ushort_t* __restrict__ Cb,
                                                    int M, int N, int K,
                                                    int ldc, int Nreal, int mode)
{
    __shared__ __align__(16) ushort_t As[2][8192];
    __shared__ __align__(16) ushort_t Bs[2][8192];
    const int tid = threadIdx.x;
    const int wv = tid >> 6, lane = tid & 63, l16 = lane & 15, quad = lane >> 4;
    const int wm = wv >> 1, wn = wv & 1;
    const int m0 = blockIdx.y * 128, n0 = blockIdx.x * 128;
    const int srow = lane >> 3;                  // 0..7 within 8-row chunk
    const int sch  = ((lane & 7) ^ srow) * 8;    // swizzled source chunk (ushorts)

    f32x4 acc[16];
#pragma unroll
    for (int i = 0; i < 16; i++) acc[i] = (f32x4)(0.f);

    // prologue: stage k0=0 into buf 0
#pragma unroll
    for (int p = 0; p < 4; p++) {
        int g = wv + p*4, row = g*8 + srow;
        int rowb = n0 + row; if (rowb > Nreal - 1) rowb = Nreal - 1;
        gl_lds16(A  + (size_t)(m0 + row) * K + sch, &As[0][g*512]);
        gl_lds16(Bm + (size_t)rowb * K + sch,       &Bs[0][g*512]);
    }
    __syncthreads();

    int cur = 0;
    for (int k0 = 0; k0 < K; k0 += 64) {
        if (k0 + 64 < K) {
#pragma unroll
            for (int p = 0; p < 4; p++) {
                int g = wv + p*4, row = g*8 + srow;
                int rowb = n0 + row; if (rowb > Nreal - 1) rowb = Nreal - 1;
                gl_lds16(A  + (size_t)(m0 + row) * K + k0 + 64 + sch, &As[cur^1][g*512]);
                gl_lds16(Bm + (size_t)rowb * K + k0 + 64 + sch,       &Bs[cur^1][g*512]);
            }
        }
#pragma unroll
        for (int ks = 0; ks < 2; ks++) {
            bf16x8 af[4], bfr[4];
#pragma unroll
            for (int mt = 0; mt < 4; mt++) {
                int row = wm*64 + mt*16 + l16;
                af[mt] = *(const bf16x8*)(&As[cur][row*64 + (((ks*4+quad) ^ (l16&7))*8)]);
            }
#pragma unroll
            for (int nt = 0; nt < 4; nt++) {
                int row = wn*64 + nt*16 + l16;
                bfr[nt] = *(const bf16x8*)(&Bs[cur][row*64 + (((ks*4+quad) ^ (l16&7))*8)]);
            }
#pragma unroll
            for (int mt = 0; mt < 4; mt++)
#pragma unroll
                for (int nt = 0; nt < 4; nt++)
                    acc[mt*4+nt] = __builtin_amdgcn_mfma_f32_16x16x32_bf16(af[mt], bfr[nt], acc[mt*4+nt], 0, 0, 0);
        }
        __syncthreads();
        cur ^= 1;
    }
#pragma unroll
    for (int mt = 0; mt < 4; mt++)
#pragma unroll
        for (int nt = 0; nt < 4; nt++) {
            int cc = n0 + wn*64 + nt*16 + l16;
            if (cc < Nreal) {
#pragma unroll
                for (int r = 0; r < 4; r++) {
                    size_t rr = m0 + wm*64 + mt*16 + quad*4 + r;
                    float v = acc[mt*4+nt][r];
                    if (mode == 1)      Cb[rr*ldc + cc] = f2bf(v);
                    else if (mode == 2) Cf[rr*ldc + cc] += v;
                    else                Cf[rr*ldc + cc] = v;
                }
            }
        }
}

// ---------------------------------------------------------------------------
// Fused Ootomo kv-projection: C[M,576] = xhi@whi^T + xlo@whi^T + xhi@wlo^T,
// f32 store. Tile 128x128, K=2048, single-buffered 64 KB LDS (2 blocks/CU).
// ---------------------------------------------------------------------------
__global__ __launch_bounds__(256, 2) void gemm_kv3(const ushort_t* __restrict__ Ahg,
                                                   const ushort_t* __restrict__ Alg,
                                                   const ushort_t* __restrict__ Bhg,
                                                   const ushort_t* __restrict__ Blg,
                                                   float* __restrict__ Cf)
{
    __shared__ __align__(16) ushort_t Ah[8192];
    __shared__ __align__(16) ushort_t Al[8192];
    __shared__ __align__(16) ushort_t Bh[8192];
    __shared__ __align__(16) ushort_t Bl[8192];
    const int tid = threadIdx.x;
    const int wv = tid >> 6, lane = tid & 63, l16 = lane & 15, quad = lane >> 4;
    const int wm = wv >> 1, wn = wv & 1;
    const int m0 = blockIdx.y * 128, n0 = blockIdx.x * 128;
    const int srow = lane >> 3;
    const int sch  = ((lane & 7) ^ srow) * 8;
    const int K = 2048;

    f32x4 acc[16];
#pragma unroll
    for (int i = 0; i < 16; i++) acc[i] = (f32x4)(0.f);

    for (int k0 = 0; k0 < K; k0 += 64) {
#pragma unroll
        for (int p = 0; p < 4; p++) {
            int g = wv + p*4, row = g*8 + srow;
            int rowb = n0 + row; if (rowb > 575) rowb = 575;
            gl_lds16(Ahg + (size_t)(m0 + row)*K + k0 + sch, Ah + g*512);
            gl_lds16(Alg + (size_t)(m0 + row)*K + k0 + sch, Al + g*512);
            gl_lds16(Bhg + (size_t)rowb*K + k0 + sch,       Bh + g*512);
            gl_lds16(Blg + (size_t)rowb*K + k0 + sch,       Bl + g*512);
        }
        __syncthreads();
#pragma unroll
        for (int ks = 0; ks < 2; ks++) {
            bf16x8 ah[4], al[4], bh[4], bl[4];
#pragma unroll
            for (int mt = 0; mt < 4; mt++) {
                int off = (wm*64 + mt*16 + l16)*64 + (((ks*4+quad) ^ (l16&7))*8);
                ah[mt] = *(const bf16x8*)(Ah + off);
                al[mt] = *(const bf16x8*)(Al + off);
            }
#pragma unroll
            for (int nt = 0; nt < 4; nt++) {
                int off = (wn*64 + nt*16 + l16)*64 + (((ks*4+quad) ^ (l16&7))*8);
                bh[nt] = *(const bf16x8*)(Bh + off);
                bl[nt] = *(const bf16x8*)(Bl + off);
            }
#pragma unroll
            for (int mt = 0; mt < 4; mt++)
#pragma unroll
                for (int nt = 0; nt < 4; nt++) {
                    acc[mt*4+nt] = __builtin_amdgcn_mfma_f32_16x16x32_bf16(ah[mt], bh[nt], acc[mt*4+nt], 0, 0, 0);
                    acc[mt*4+nt] = __builtin_amdgcn_mfma_f32_16x16x32_bf16(al[mt], bh[nt], acc[mt*4+nt], 0, 0, 0);
                    acc[mt*4+nt] = __builtin_amdgcn_mfma_f32_16x16x32_bf16(ah[mt], bl[nt], acc[mt*4+nt], 0, 0, 0);
                }
        }
        __syncthreads();
    }
#pragma unroll
    for (int mt = 0; mt < 4; mt++)
#pragma unroll
        for (int nt = 0; nt < 4; nt++) {
            int cc = n0 + wn*64 + nt*16 + l16;
            if (cc < 576) {
#pragma unroll
                for (int r = 0; r < 4; r++) {
                    size_t rr = m0 + wm*64 + mt*16 + quad*4 + r;
                    Cf[rr*576 + cc] = acc[mt*4+nt][r];
                }
            }
        }
}

// ---------------------------------------------------------------------------
// V' GEMM: vpT[b][h][c][t] = sum_k kvn[b,t,k] * wbv[h,c,k]. Tile 128x128, K=512.
// ---------------------------------------------------------------------------
__global__ __launch_bounds__(256, 2) void gemm_vp(const ushort_t* __restrict__ kvnb,
                                                  const ushort_t* __restrict__ wbvB,
                                                  ushort_t* __restrict__ vpT)
{
    __shared__ __align__(16) ushort_t As[2][8192];
    __shared__ __align__(16) ushort_t Bs[2][8192];
    const int tid = threadIdx.x;
    const int wv = tid >> 6, lane = tid & 63, l16 = lane & 15, quad = lane >> 4;
    const int wm = wv >> 1, wn = wv & 1;
    const int m0 = blockIdx.x * 128;
    const int h  = blockIdx.y;
    const ushort_t* Bh = wbvB + h*65536;
    const int srow = lane >> 3;
    const int sch  = ((lane & 7) ^ srow) * 8;

    f32x4 acc[16];
#pragma unroll
    for (int i = 0; i < 16; i++) acc[i] = (f32x4)(0.f);

#pragma unroll
    for (int p = 0; p < 4; p++) {
        int g = wv + p*4, row = g*8 + srow;
        gl_lds16(kvnb + (size_t)(m0 + row)*512 + sch, &As[0][g*512]);
        gl_lds16(Bh   + (size_t)row*512 + sch,        &Bs[0][g*512]);
    }
    __syncthreads();

    int cur = 0;
    for (int k0 = 0; k0 < 512; k0 += 64) {
        if (k0 + 64 < 512) {
#pragma unroll
            for (int p = 0; p < 4; p++) {
                int g = wv + p*4, row = g*8 + srow;
                gl_lds16(kvnb + (size_t)(m0 + row)*512 + k0 + 64 + sch, &As[cur^1][g*512]);
                gl_lds16(Bh   + (size_t)row*512 + k0 + 64 + sch,        &Bs[cur^1][g*512]);
            }
        }
#pragma unroll
        for (int ks = 0; ks < 2; ks++) {
            bf16x8 af[4], bfr[4];
#pragma unroll
            for (int mt = 0; mt < 4; mt++) {
                int row = wm*64 + mt*16 + l16;
                af[mt] = *(const bf16x8*)(&As[cur][row*64 + (((ks*4+quad) ^ (l16&7))*8)]);
            }
#pragma unroll
            for (int nt = 0; nt < 4; nt++) {
                int row = wn*64 + nt*16 + l16;
                bfr[nt] = *(const bf16x8*)(&Bs[cur][row*64 + (((ks*4+quad) ^ (l16&7))*8)]);
            }
#pragma unroll
            for (int mt = 0; mt < 4; mt++)
#pragma unroll
                for (int nt = 0; nt < 4; nt++)
                    acc[mt*4+nt] = __builtin_amdgcn_mfma_f32_16x16x32_bf16(af[mt], bfr[nt], acc[mt*4+nt], 0, 0, 0);
        }
        __syncthreads();
        cur ^= 1;
    }
    // scatter: 4 consecutive t per lane -> uint2
#pragma unroll
    for (int mt = 0; mt < 4; mt++)
#pragma unroll
        for (int nt = 0; nt < 4; nt++) {
            int rr = m0 + wm*64 + mt*16 + quad*4;
            int bb = rr >> 11, t = rr & 2047;
            int cc = wn*64 + nt*16 + l16;
            ushort_t pk[4];
#pragma unroll
            for (int r = 0; r < 4; r++) pk[r] = f2bf(acc[mt*4+nt][r]);
            *(uint2*)(vpT + ((size_t)((bb*16 + h)*128 + cc))*2048 + t) = *(const uint2*)pk;
        }
}

// ---------------------------------------------------------------------------
// K' GEMM: kpb[b][h][t][d] = scale * sum_c kvn[b,t,c] * wbkN[h,d,c].
// Tile 128x128 (N=128 exactly), K=512, row-major [t][128] bf16 store.
// ---------------------------------------------------------------------------
__global__ __launch_bounds__(256, 2) void gemm_kp(const ushort_t* __restrict__ kvnb,
                                                  const ushort_t* __restrict__ wbkN,
                                                  ushort_t* __restrict__ kpb)
{
    __shared__ __align__(16) ushort_t As[2][8192];
    __shared__ __align__(16) ushort_t Bs[2][8192];
    const int tid = threadIdx.x;
    const int wv = tid >> 6, lane = tid & 63, l16 = lane & 15, quad = lane >> 4;
    const int wm = wv >> 1, wn = wv & 1;
    const int m0 = blockIdx.x * 128;
    const int h  = blockIdx.y;
    const ushort_t* Bh = wbkN + h*65536;
    const int srow = lane >> 3;
    const int sch  = ((lane & 7) ^ srow) * 8;
    const float scale = 0.07216878364870323f;   // 192^-0.5 folded into K'

    f32x4 acc[16];
#pragma unroll
    for (int i = 0; i < 16; i++) acc[i] = (f32x4)(0.f);

#pragma unroll
    for (int p = 0; p < 4; p++) {
        int g = wv + p*4, row = g*8 + srow;
        gl_lds16(kvnb + (size_t)(m0 + row)*512 + sch, &As[0][g*512]);
        gl_lds16(Bh   + (size_t)row*512 + sch,        &Bs[0][g*512]);
    }
    __syncthreads();

    int cur = 0;
    for (int k0 = 0; k0 < 512; k0 += 64) {
        if (k0 + 64 < 512) {
#pragma unroll
            for (int p = 0; p < 4; p++) {
                int g = wv + p*4, row = g*8 + srow;
                gl_lds16(kvnb + (size_t)(m0 + row)*512 + k0 + 64 + sch, &As[cur^1][g*512]);
                gl_lds16(Bh   + (size_t)row*512 + k0 + 64 + sch,        &Bs[cur^1][g*512]);
            }
        }
#pragma unroll
        for (int ks = 0; ks < 2; ks++) {
            bf16x8 af[4], bfr[4];
#pragma unroll
            for (int mt = 0; mt < 4; mt++) {
                int row = wm*64 + mt*16 + l16;
                af[mt] = *(const bf16x8*)(&As[cur][row*64 + (((ks*4+quad) ^ (l16&7))*8)]);
            }
#pragma unroll
            for (int nt = 0; nt < 4; nt++) {
                int row = wn*64 + nt*16 + l16;
                bfr[nt] = *(const bf16x8*)(&Bs[cur][row*64 + (((ks*4+quad) ^ (l16&7))*8)]);
            }
#pragma unroll
            for (int mt = 0; mt < 4; mt++)
#pragma unroll
                for (int nt = 0; nt < 4; nt++)
                    acc[mt*4+nt] = __builtin_amdgcn_mfma_f32_16x16x32_bf16(af[mt], bfr[nt], acc[mt*4+nt], 0, 0, 0);
        }
        __syncthreads();
        cur ^= 1;
    }
    // row-major [t][128] store, scale folded; 16-lane groups write 32B runs
#pragma unroll
    for (int mt = 0; mt < 4; mt++)
#pragma unroll
        for (int nt = 0; nt < 4; nt++) {
            int cc = wn*64 + nt*16 + l16;
#pragma unroll
            for (int r = 0; r < 4; r++) {
                int rr = m0 + wm*64 + mt*16 + quad*4 + r;
                int bb = rr >> 11, t = rr & 2047;
                kpb[((size_t)((bb*16 + h)*2048 + t))*128 + cc] = f2bf(acc[mt*4+nt][r] * scale);
            }
        }
}

// ---------------------------------------------------------------------------
__global__ __launch_bounds__(256) void prep_wb(const float* __restrict__ wkv_b,
                                               ushort_t* __restrict__ wbkN,
                                               ushort_t* __restrict__ wbvB)
{
    int u = blockIdx.x * 256 + threadIdx.x;
    int h = u >> 16, rem = u & 65535;
    wbkN[u] = f2bf(wkv_b[h*131072 + rem]);            // [h][d][c] natural rows
    wbvB[u] = f2bf(wkv_b[h*131072 + 65536 + rem]);
}

// ---------------------------------------------------------------------------
__global__ __launch_bounds__(256) void kv_norm_rope(const float* __restrict__ kvr,
                                                    const float* __restrict__ w,
                                                    const float* __restrict__ cosT,
                                                    const float* __restrict__ sinT,
                                                    ushort_t* __restrict__ kvnb,
                                                    ushort_t* __restrict__ kpeb)
{
    const int bs   = blockIdx.x * 4 + (threadIdx.x >> 6);
    const int lane = threadIdx.x & 63;
    const int s    = bs & (S_ - 1);
    const float* row = kvr + bs * 576;
    const float scale = 0.07216878364870323f;   // folded into k_pe

    float4 v0 = *(const float4*)(row + lane*8);
    float4 v1 = *(const float4*)(row + lane*8 + 4);
    float ss = v0.x*v0.x + v0.y*v0.y + v0.z*v0.z + v0.w*v0.w
             + v1.x*v1.x + v1.y*v1.y + v1.z*v1.z + v1.w*v1.w;
#pragma unroll
    for (int off = 32; off >= 1; off >>= 1) ss += __shfl_xor(ss, off);
    const float rs = rsqrtf(ss * (1.0f/512.0f) + 1e-6f);

    float4 w0 = *(const float4*)(w + lane*8);
    float4 w1 = *(const float4*)(w + lane*8 + 4);
    float o[8];
    o[0] = v0.x*rs*w0.x; o[1] = v0.y*rs*w0.y; o[2] = v0.z*rs*w0.z; o[3] = v0.w*rs*w0.w;
    o[4] = v1.x*rs*w1.x; o[5] = v1.y*rs*w1.y; o[6] = v1.z*rs*w1.z; o[7] = v1.w*rs*w1.w;

    ushort_t pk[8];
#pragma unroll
    for (int p = 0; p < 8; p++) pk[p] = f2bf(o[p]);
    *(uint4*)(kvnb + (size_t)bs*512 + lane*8) = *(const uint4*)pk;

    if (lane < 32) {
        float xr = row[512 + 2*lane], xi = row[512 + 2*lane + 1];
        float c  = cosT[s*32 + lane], sn = sinT[s*32 + lane];
        ushort_t p2[2] = { f2bf((xr*c - xi*sn)*scale), f2bf((xr*sn + xi*c)*scale) };
        *(uint_t*)(kpeb + (size_t)bs*64 + 2*lane) = *(const uint_t*)p2;
    }
}

// ---------------------------------------------------------------------------
// stage one 32-key tile: K'|kpe (12 frag-groups) -> F[buf], V' (8) -> V[buf].
// lane-linear frag layout; wave w issues its subset (20 groups / 8 waves).
// ---------------------------------------------------------------------------
__device__ __forceinline__ void stage_tile(const ushort_t* kp_h, const ushort_t* kpe_b,
                                           const ushort_t* vpT_h, ushort_t* ldsb,
                                           int t0, int buf, int w, int l16, int q8e)
{
    ushort_t* Fb = ldsb + buf*6144;
    ushort_t* Vb = ldsb + 12288 + buf*4096;
#pragma unroll
    for (int ii = 0; ii < 3; ii++) {
        int i = w + ii*8;
        if (i < 12) {
            int g2 = (i >= 6) ? 1 : 0;
            int ks = i - g2*6;
            int row = t0 + g2*16 + l16;
            const ushort_t* src = (ks < 4)
                ? (kp_h + (size_t)row*128 + ks*32 + q8e)
                : (kpe_b + (size_t)row*64 + (ks-4)*32 + q8e);
            gl_lds16(src, Fb + i*512);
        } else if (i < 20) {
            int gv = i - 12;
            const ushort_t* src = vpT_h + (size_t)(gv*16 + l16)*2048 + t0 + q8e;
            gl_lds16(src, Vb + gv*512);
        }
    }
}

// ---------------------------------------------------------------------------
// MFMA flash attention v12: K-absorbed. 128 q-rows/block, 8 waves x 16 rows,
// S^T inner dim 192 (12 MFMA), qf[6], double-buffered 50 KB LDS, 1 barrier/tile.
// ---------------------------------------------------------------------------
__global__ __launch_bounds__(512, 2) void attn_mfma(
    const ushort_t* __restrict__ qb,
    const ushort_t* __restrict__ kpb,
    const ushort_t* __restrict__ kpeb,
    const ushort_t* __restrict__ vpT,
    const float* __restrict__ cosT,
    const float* __restrict__ sinT,
    ushort_t* __restrict__ ovb)
{
    // XCD/LPT swizzle: batch = flat&1, longest causal blocks first
    const int flat = blockIdx.x + 16*blockIdx.y + 256*blockIdx.z;
    const int b    = flat & 1;
    const int rem  = flat >> 1;
    const int h    = rem & 15;
    const int q0   = (15 - (rem >> 4)) << 7;

    const int tid  = threadIdx.x;
    const int w    = tid >> 6;
    const int lane = tid & 63;
    const int l16  = lane & 15;
    const int quad = lane >> 4;
    const int tl   = quad * 4;
    const int lb   = lane & 48;
    const int q8e  = quad * 8;

    // LDS map (ushort elems): F[buf]=buf*6144 (12KB x2); V[buf]=12288+buf*4096
    // (8KB x2); pt = 20480 + w*640. Total 25600 ushorts = 51200 B.
    __shared__ __align__(16) ushort_t lds[25600];

    const ushort_t* kp_h  = kpb + (size_t)(b*16 + h)*2048*128;
    const ushort_t* kpe_b = kpeb + (size_t)b*S_*64;
    const ushort_t* vpT_h = vpT + (size_t)(b*16 + h)*128*2048;

    const int r0    = q0 + w*16;
    const int rglob = r0 + l16;

    // ---- prologue: stage tile 0 into buf 0 (overlaps qf build)
    stage_tile(kp_h, kpe_b, vpT_h, lds, 0, 0, w, l16, q8e);

    // ===== qf[0..3] = q_nope frags (raw), qf[4..5] = rope(q_pe) (raw) =====
    const ushort_t* qrow = qb + (size_t)(b*S_ + rglob)*3072 + h*192;
    bf16x8 qf[6];
#pragma unroll
    for (int ks = 0; ks < 4; ks++)
        qf[ks] = *(const bf16x8*)(qrow + ks*32 + q8e);
#pragma unroll
    for (int kk = 0; kk < 2; kk++) {
        int off = kk*32 + q8e;
        uint4 pv4 = *(const uint4*)(qrow + 128 + off);
        const ushort_t* pe = (const ushort_t*)&pv4;
        ushort_t pk[8];
#pragma unroll
        for (int u2 = 0; u2 < 4; u2++) {
            float xr = bf2f(pe[2*u2]), xi = bf2f(pe[2*u2+1]);
            int pi = (off >> 1) + u2;
            float c = cosT[rglob*32 + pi], sn = sinT[rglob*32 + pi];
            pk[2*u2]   = f2bf(xr*c  - xi*sn);
            pk[2*u2+1] = f2bf(xr*sn + xi*c );
        }
        qf[4 + kk] = *(const bf16x8*)pk;
    }
    __syncthreads();   // tile0 staging drained

    // ===== flash main loop: TK=32, double-buffered, 1 barrier/tile =====
    f32x4 o[8];
#pragma unroll
    for (int n = 0; n < 8; n++) o[n] = (f32x4)(0.f);
    float m_s = -1e30f, l_s = 0.f;

    const int bniter = (q0 >> 5) + 4;            // block-uniform tile count
    const int wniter = ((r0 + 15) >> 5) + 1;     // this wave's causal bound
    ushort_t* ptw = lds + 20480 + w*640;
    int cur = 0;

#pragma unroll 1
    for (int it = 0; it < bniter; it++) {
        if (it + 1 < bniter)
            stage_tile(kp_h, kpe_b, vpT_h, lds, (it+1)*32, cur ^ 1, w, l16, q8e);

        if (it < wniter) {
            const int t0 = it * 32;
            const ushort_t* Fb = lds + cur*6144;
            const ushort_t* Vb = lds + 12288 + cur*4096;

            // S^T over 192 dims: C col = q-row (l16), C row = key (tl+reg)
            __builtin_amdgcn_s_setprio(1);
            f32x4 s0 = (f32x4)(0.f), s1 = (f32x4)(0.f);
#pragma unroll
            for (int ks = 0; ks < 6; ks++) {
                bf16x8 kf0 = *(const bf16x8*)(Fb + ks*512 + lane*8);
                s0 = __builtin_amdgcn_mfma_f32_16x16x32_bf16(kf0, qf[ks], s0, 0, 0, 0);
                bf16x8 kf1 = *(const bf16x8*)(Fb + 3072 + ks*512 + lane*8);
                s1 = __builtin_amdgcn_mfma_f32_16x16x32_bf16(kf1, qf[ks], s1, 0, 0, 0);
            }
            __builtin_amdgcn_s_setprio(0);

            // online softmax for q-row rglob (scale already folded into K',kpe)
            float pv[8];
            float mx = -1e30f;
#pragma unroll
            for (int reg = 0; reg < 4; reg++) {
                pv[reg]   = ((t0 + tl + reg)      <= rglob) ? s0[reg] : -1e30f;
                pv[4+reg] = ((t0 + 16 + tl + reg) <= rglob) ? s1[reg] : -1e30f;
                mx = fmaxf(mx, fmaxf(pv[reg], pv[4+reg]));
            }
            mx = fmaxf(mx, __shfl_xor(mx, 16));
            mx = fmaxf(mx, __shfl_xor(mx, 32));
            if (!__all(mx <= m_s)) {        // exact skip when max unchanged
                float mn = fmaxf(m_s, mx);
                float al = __expf(m_s - mn);
                m_s = mn;
                l_s *= al;
                f32x4 alv;
#pragma unroll
                for (int reg = 0; reg < 4; reg++) alv[reg] = __shfl(al, lb + tl + reg, 64);
#pragma unroll
                for (int n = 0; n < 8; n++) o[n] *= alv;
            }
            float ps = 0.f;
#pragma unroll
            for (int reg = 0; reg < 8; reg++) {
                pv[reg] = (pv[reg] > -1e29f) ? __expf(pv[reg] - m_s) : 0.f;
                ps += pv[reg];
            }
            ps += __shfl_xor(ps, 16);
            ps += __shfl_xor(ps, 32);
            l_s += ps;

            // P^T -> ptw (per-wave), fence, read back A-frag (k=32)
            ushort_t pk4[8];
#pragma unroll
            for (int reg = 0; reg < 8; reg++) pk4[reg] = f2bf(pv[reg]);
            *(uint2*)(ptw + l16*40 + tl)      = *(const uint2*)(pk4);
            *(uint2*)(ptw + l16*40 + 16 + tl) = *(const uint2*)(pk4 + 4);
            asm volatile("" ::: "memory");
            bf16x8 ap = *(const bf16x8*)(ptw + l16*40 + q8e);
            asm volatile("" ::: "memory");

            // PV': o[n] += P[r][t] * V'[t][c], c = n*16 + l16 (128-dim output)
            __builtin_amdgcn_s_setprio(1);
#pragma unroll
            for (int n = 0; n < 8; n++) {
                bf16x8 bv = *(const bf16x8*)(Vb + n*512 + lane*8);
                o[n] = __builtin_amdgcn_mfma_f32_16x16x32_bf16(ap, bv, o[n], 0, 0, 0);
            }
            __builtin_amdgcn_s_setprio(0);
        }
        __syncthreads();   // next-tile staging drained + cur-buffer reads done
        cur ^= 1;
    }

    // ===== output: ovb = o / l =====
    float linv = 1.f / l_s;
    f32x4 rlv;
#pragma unroll
    for (int reg = 0; reg < 4; reg++) rlv[reg] = __shfl(linv, lb + tl + reg, 64);

    ushort_t* orow = ovb + (size_t)(b*S_ + r0)*2048 + h*128;
#pragma unroll
    for (int n = 0; n < 8; n++)
#pragma unroll
        for (int reg = 0; reg < 4; reg++)
            orow[(size_t)(tl + reg)*2048 + n*16 + l16] = f2bf(o[n][reg] * rlv[reg]);
}

// ---------------------------------------------------------------------------
extern "C" void kernel_launch(void* const* d_in, const int* in_sizes, int n_in,
                              void* d_out, int out_size, void* d_ws, size_t ws_size,
                              hipStream_t stream) {
    const float* x     = (const float*)d_in[0];
    const float* cosT  = (const float*)d_in[1];
    const float* sinT  = (const float*)d_in[2];
    // d_in[3] mask: unused (causality applied directly)
    const float* wq    = (const float*)d_in[4];
    const float* wkv_a = (const float*)d_in[5];
    const float* kvw   = (const float*)d_in[6];
    const float* wkv_b = (const float*)d_in[7];
    const float* wo    = (const float*)d_in[8];
    float* out = (float*)d_out;

    ushort_t* qb   = (ushort_t*)d_ws;       // 4096x3072 bf16
    ushort_t* xb   = qb   + 12582912;       // 4096x2048 x-hi; later vpT
    ushort_t* wqb  = xb   + 8388608;        // 3072x2048; later wa_hi/wa_lo, then kpb
    ushort_t* wob  = wqb  + 6291456;        // 2048x2048 (cast AFTER attn; head = kpb tail)
    ushort_t* ovb  = wob  + 4194304;        // x-lo early; attn output later
    ushort_t* kvnb = ovb  + 8388608;        // 4096x512
    ushort_t* kpeb = kvnb + 2097152;        // 4096x64
    ushort_t* kvnT = kpeb + 262144;         // unused slot
    ushort_t* wbkN = kvnT + 2097152;        // 16x128x512 (natural layout)
    ushort_t* wbvB = wbkN + 1048576;        // 16x128x512
    float*    kvr  = (float*)(wbvB + 1048576);  // 4096x576 f32

    ushort_t* xlo  = ovb;                   // 4096x2048 bf16 (dead until attn)
    ushort_t* wahi = wqb;                   // 576x2048 bf16 (after q-proj)
    ushort_t* walo = wqb + 1179648;         // 576x2048 bf16
    ushort_t* vpT  = xb;                    // 2x16x128x2048 (after kv gemms)
    ushort_t* kpb  = wqb;                   // 2x16x2048x128 (after gemm_kv3; spills
                                            // 2097152 into wob head - wo cast later)

    dim3 blk(256);
    cast2_bf16<<<dim3(8192), blk, 0, stream>>>(x, xb, xlo, 8388608);
    cast_bf16<<<dim3(6144), blk, 0, stream>>>(wq, wqb, 6291456);
    prep_wb<<<dim3(4096), blk, 0, stream>>>(wkv_b, wbkN, wbvB);
    gemm_bf16<<<dim3(24, 32), blk, 0, stream>>>(xb, wqb, nullptr, qb, 4096, 3072, 2048, 3072, 3072, 1);
    cast2_bf16<<<dim3(1152), blk, 0, stream>>>(wkv_a, wahi, walo, 1179648);
    gemm_kv3<<<dim3(5, 32), blk, 0, stream>>>(xb, xlo, wahi, walo, kvr);
    kv_norm_rope<<<dim3(1024), blk, 0, stream>>>(kvr, kvw, cosT, sinT, kvnb, kpeb);
    gemm_vp<<<dim3(32, 16), blk, 0, stream>>>(kvnb, wbvB, vpT);
    gemm_kp<<<dim3(32, 16), blk, 0, stream>>>(kvnb, wbkN, kpb);
    attn_mfma<<<dim3(16, 16, 2), dim3(512), 0, stream>>>(qb, kpb, kpeb, vpT, cosT, sinT, ovb);
    cast_bf16<<<dim3(4096), blk, 0, stream>>>(wo, wob, 4194304);
    gemm_bf16<<<dim3(16, 32), blk, 0, stream>>>(ovb, wob, out, nullptr, 4096, 2048, 2048, 2048, 2048, 0);
}

// Round 12
// 460.499 us; speedup vs baseline: 2.2509x; 1.0399x over previous
//
#include <hip/hip_runtime.h>
#include <hip/hip_bf16.h>

// MLA forward, round 18 (= round 17 resubmit; container infra failure last
// round; __builtin_amdgcn_exp2f swapped for exp2f to remove compile risk):
//  - attn VALU cuts: log2e folded into K'/kpe scale -> exp2 (no pre-mul),
//    v_cvt_pk_bf16_f32 P-pack, unmasked fast path for full tiles, guard-free
//    exp (exp2 of -1e30-m underflows to 0 exactly).
//  - gemm_vp + gemm_kp merged into gemm_vk: stage kvn A-tile once, both B
//    chains (wbk | wbv), 48 KB single-buffered, 512 blocks = 2/CU.
//  - rest verbatim r16 (K-side absorption, fused kv3, m97 GEMMs, LPT swizzle).
// B=2 S=2048 D=2048 H=16 NOPE=128 ROPE=64 V=128 C=512
#define B_ 2
#define S_ 2048
#define H_ 16

typedef unsigned short ushort_t;
typedef unsigned int uint_t;
typedef __attribute__((ext_vector_type(8))) short bf16x8;
typedef __attribute__((ext_vector_type(4))) float f32x4;

__device__ __forceinline__ ushort_t f2bf(float f) {
    uint_t u = __float_as_uint(f);
    return (ushort_t)((u + 0x7fffu + ((u >> 16) & 1u)) >> 16);
}
__device__ __forceinline__ float bf2f(ushort_t v) {
    return __uint_as_float(((uint_t)v) << 16);
}

// global -> LDS direct copy, 16B per lane. LDS dest wave-uniform; HW writes
// lane i at ldsbase + i*16. Global src per-lane.
__device__ __forceinline__ void gl_lds16(const ushort_t* g, ushort_t* l) {
    __builtin_amdgcn_global_load_lds(
        (const __attribute__((address_space(1))) unsigned int*)(unsigned long long)g,
        (__attribute__((address_space(3))) unsigned int*)(unsigned int)(unsigned long long)l,
        16, 0, 0);
}

// ---------------------------------------------------------------------------
// f32 -> bf16 cast
// ---------------------------------------------------------------------------
__global__ __launch_bounds__(256) void cast_bf16(const float* __restrict__ src,
                                                 ushort_t* __restrict__ dst, int n)
{
    int i = (blockIdx.x * 256 + threadIdx.x) * 4;
    if (i < n) {
        float4 v = *(const float4*)(src + i);
        ushort_t pk[4] = { f2bf(v.x), f2bf(v.y), f2bf(v.z), f2bf(v.w) };
        *(uint2*)(dst + i) = *(const uint2*)pk;
    }
}

// f32 -> bf16 hi + bf16 lo (residual) split cast
__global__ __launch_bounds__(256) void cast2_bf16(const float* __restrict__ src,
                                                  ushort_t* __restrict__ hi,
                                                  ushort_t* __restrict__ lo, int n)
{
    int i = (blockIdx.x * 256 + threadIdx.x) * 4;
    if (i < n) {
        float4 v = *(const float4*)(src + i);
        float vv[4] = { v.x, v.y, v.z, v.w };
        ushort_t ph[4], pl[4];
#pragma unroll
        for (int k = 0; k < 4; k++) {
            ph[k] = f2bf(vv[k]);
            pl[k] = f2bf(vv[k] - bf2f(ph[k]));
        }
        *(uint2*)(hi + i) = *(const uint2*)ph;
        *(uint2*)(lo + i) = *(const uint2*)pl;
    }
}

// ---------------------------------------------------------------------------
// bf16 MFMA GEMM (m97-style): C[M,N] = A[M,K] @ B[N,K]^T. M%128==0, N%128==0
// (tiling), K%64==0. Nreal guards B-row reads and C stores; ldc = C stride.
// mode: 0 = f32 store, 1 = bf16 store, 2 = f32 accumulate.
// ---------------------------------------------------------------------------
__global__ __launch_bounds__(256, 2) void gemm_bf16(const ushort_t* __restrict__ A,
                                                    const ushort_t* __restrict__ Bm,
                                                    float* __restrict__ Cf,
                                                    ushort_t* __restrict__ Cb,
                                                    int M, int N, int K,
                                                    int ldc, int Nreal, int mode)
{
    __shared__ __align__(16) ushort_t As[2][8192];
    __shared__ __align__(16) ushort_t Bs[2][8192];
    const int tid = threadIdx.x;
    const int wv = tid >> 6, lane = tid & 63, l16 = lane & 15, quad = lane >> 4;
    const int wm = wv >> 1, wn = wv & 1;
    const int m0 = blockIdx.y * 128, n0 = blockIdx.x * 128;
    const int srow = lane >> 3;                  // 0..7 within 8-row chunk
    const int sch  = ((lane & 7) ^ srow) * 8;    // swizzled source chunk (ushorts)

    f32x4 acc[16];
#pragma unroll
    for (int i = 0; i < 16; i++) acc[i] = (f32x4)(0.f);

    // prologue: stage k0=0 into buf 0
#pragma unroll
    for (int p = 0; p < 4; p++) {
        int g = wv + p*4, row = g*8 + srow;
        int rowb = n0 + row; if (rowb > Nreal - 1) rowb = Nreal - 1;
        gl_lds16(A  + (size_t)(m0 + row) * K + sch, &As[0][g*512]);
        gl_lds16(Bm + (size_t)rowb * K + sch,       &Bs[0][g*512]);
    }
    __syncthreads();

    int cur = 0;
    for (int k0 = 0; k0 < K; k0 += 64) {
        if (k0 + 64 < K) {
#pragma unroll
            for (int p = 0; p < 4; p++) {
                int g = wv + p*4, row = g*8 + srow;
                int rowb = n0 + row; if (rowb > Nreal - 1) rowb = Nreal - 1;
                gl_lds16(A  + (size_t)(m0 + row) * K + k0 + 64 + sch, &As[cur^1][g*512]);
                gl_lds16(Bm + (size_t)rowb * K + k0 + 64 + sch,       &Bs[cur^1][g*512]);
            }
        }
#pragma unroll
        for (int ks = 0; ks < 2; ks++) {
            bf16x8 af[4], bfr[4];
#pragma unroll
            for (int mt = 0; mt < 4; mt++) {
                int row = wm*64 + mt*16 + l16;
                af[mt] = *(const bf16x8*)(&As[cur][row*64 + (((ks*4+quad) ^ (l16&7))*8)]);
            }
#pragma unroll
            for (int nt = 0; nt < 4; nt++) {
                int row = wn*64 + nt*16 + l16;
                bfr[nt] = *(const bf16x8*)(&Bs[cur][row*64 + (((ks*4+quad) ^ (l16&7))*8)]);
            }
#pragma unroll
            for (int mt = 0; mt < 4; mt++)
#pragma unroll
                for (int nt = 0; nt < 4; nt++)
                    acc[mt*4+nt] = __builtin_amdgcn_mfma_f32_16x16x32_bf16(af[mt], bfr[nt], acc[mt*4+nt], 0, 0, 0);
        }
        __syncthreads();
        cur ^= 1;
    }
#pragma unroll
    for (int mt = 0; mt < 4; mt++)
#pragma unroll
        for (int nt = 0; nt < 4; nt++) {
            int cc = n0 + wn*64 + nt*16 + l16;
            if (cc < Nreal) {
#pragma unroll
                for (int r = 0; r < 4; r++) {
                    size_t rr = m0 + wm*64 + mt*16 + quad*4 + r;
                    float v = acc[mt*4+nt][r];
                    if (mode == 1)      Cb[rr*ldc + cc] = f2bf(v);
                    else if (mode == 2) Cf[rr*ldc + cc] += v;
                    else                Cf[rr*ldc + cc] = v;
                }
            }
        }
}

// ---------------------------------------------------------------------------
// Fused Ootomo kv-projection: C[M,576] = xhi@whi^T + xlo@whi^T + xhi@wlo^T,
// f32 store. Tile 128x128, K=2048, single-buffered 64 KB LDS (2 blocks/CU).
// ---------------------------------------------------------------------------
__global__ __launch_bounds__(256, 2) void gemm_kv3(const ushort_t* __restrict__ Ahg,
                                                   const ushort_t* __restrict__ Alg,
                                                   const ushort_t* __restrict__ Bhg,
                                                   const ushort_t* __restrict__ Blg,
                                                   float* __restrict__ Cf)
{
    __shared__ __align__(16) ushort_t Ah[8192];
    __shared__ __align__(16) ushort_t Al[8192];
    __shared__ __align__(16) ushort_t Bh[8192];
    __shared__ __align__(16) ushort_t Bl[8192];
    const int tid = threadIdx.x;
    const int wv = tid >> 6, lane = tid & 63, l16 = lane & 15, quad = lane >> 4;
    const int wm = wv >> 1, wn = wv & 1;
    const int m0 = blockIdx.y * 128, n0 = blockIdx.x * 128;
    const int srow = lane >> 3;
    const int sch  = ((lane & 7) ^ srow) * 8;
    const int K = 2048;

    f32x4 acc[16];
#pragma unroll
    for (int i = 0; i < 16; i++) acc[i] = (f32x4)(0.f);

    for (int k0 = 0; k0 < K; k0 += 64) {
#pragma unroll
        for (int p = 0; p < 4; p++) {
            int g = wv + p*4, row = g*8 + srow;
            int rowb = n0 + row; if (rowb > 575) rowb = 575;
            gl_lds16(Ahg + (size_t)(m0 + row)*K + k0 + sch, Ah + g*512);
            gl_lds16(Alg + (size_t)(m0 + row)*K + k0 + sch, Al + g*512);
            gl_lds16(Bhg + (size_t)rowb*K + k0 + sch,       Bh + g*512);
            gl_lds16(Blg + (size_t)rowb*K + k0 + sch,       Bl + g*512);
        }
        __syncthreads();
#pragma unroll
        for (int ks = 0; ks < 2; ks++) {
            bf16x8 ah[4], al[4], bh[4], bl[4];
#pragma unroll
            for (int mt = 0; mt < 4; mt++) {
                int off = (wm*64 + mt*16 + l16)*64 + (((ks*4+quad) ^ (l16&7))*8);
                ah[mt] = *(const bf16x8*)(Ah + off);
                al[mt] = *(const bf16x8*)(Al + off);
            }
#pragma unroll
            for (int nt = 0; nt < 4; nt++) {
                int off = (wn*64 + nt*16 + l16)*64 + (((ks*4+quad) ^ (l16&7))*8);
                bh[nt] = *(const bf16x8*)(Bh + off);
                bl[nt] = *(const bf16x8*)(Bl + off);
            }
#pragma unroll
            for (int mt = 0; mt < 4; mt++)
#pragma unroll
                for (int nt = 0; nt < 4; nt++) {
                    acc[mt*4+nt] = __builtin_amdgcn_mfma_f32_16x16x32_bf16(ah[mt], bh[nt], acc[mt*4+nt], 0, 0, 0);
                    acc[mt*4+nt] = __builtin_amdgcn_mfma_f32_16x16x32_bf16(al[mt], bh[nt], acc[mt*4+nt], 0, 0, 0);
                    acc[mt*4+nt] = __builtin_amdgcn_mfma_f32_16x16x32_bf16(ah[mt], bl[nt], acc[mt*4+nt], 0, 0, 0);
                }
        }
        __syncthreads();
    }
#pragma unroll
    for (int mt = 0; mt < 4; mt++)
#pragma unroll
        for (int nt = 0; nt < 4; nt++) {
            int cc = n0 + wn*64 + nt*16 + l16;
            if (cc < 576) {
#pragma unroll
                for (int r = 0; r < 4; r++) {
                    size_t rr = m0 + wm*64 + mt*16 + quad*4 + r;
                    Cf[rr*576 + cc] = acc[mt*4+nt][r];
                }
            }
        }
}

// ---------------------------------------------------------------------------
// Fused V'/K' GEMM: from kvn, per head h:
//   ak = kvn @ wbk[h]^T -> kpb row-major [t][128] with scale*log2e folded
//   av = kvn @ wbv[h]^T -> vpT transposed [c][t]
// Tile 128x(128+128), K=512, single-buffered 48 KB LDS, grid (32,16) = 2/CU.
// ---------------------------------------------------------------------------
__global__ __launch_bounds__(256, 2) void gemm_vk(const ushort_t* __restrict__ kvnb,
                                                  const ushort_t* __restrict__ wbkN,
                                                  const ushort_t* __restrict__ wbvB,
                                                  ushort_t* __restrict__ kpb,
                                                  ushort_t* __restrict__ vpT)
{
    __shared__ __align__(16) ushort_t As[8192];
    __shared__ __align__(16) ushort_t Bk[8192];
    __shared__ __align__(16) ushort_t Bv[8192];
    const int tid = threadIdx.x;
    const int wv = tid >> 6, lane = tid & 63, l16 = lane & 15, quad = lane >> 4;
    const int wm = wv >> 1, wn = wv & 1;
    const int m0 = blockIdx.x * 128;
    const int h  = blockIdx.y;
    const ushort_t* Bkh = wbkN + h*65536;
    const ushort_t* Bvh = wbvB + h*65536;
    const int srow = lane >> 3;
    const int sch  = ((lane & 7) ^ srow) * 8;
    const float SC2 = 0.10411756512f;   // 192^-0.5 * log2(e)

    f32x4 ak[16], av[16];
#pragma unroll
    for (int i = 0; i < 16; i++) { ak[i] = (f32x4)(0.f); av[i] = (f32x4)(0.f); }

    for (int k0 = 0; k0 < 512; k0 += 64) {
#pragma unroll
        for (int p = 0; p < 4; p++) {
            int g = wv + p*4, row = g*8 + srow;
            gl_lds16(kvnb + (size_t)(m0 + row)*512 + k0 + sch, As + g*512);
            gl_lds16(Bkh  + (size_t)row*512 + k0 + sch,        Bk + g*512);
            gl_lds16(Bvh  + (size_t)row*512 + k0 + sch,        Bv + g*512);
        }
        __syncthreads();
#pragma unroll
        for (int ks = 0; ks < 2; ks++) {
            bf16x8 af[4], bkf[4], bvf[4];
#pragma unroll
            for (int mt = 0; mt < 4; mt++)
                af[mt] = *(const bf16x8*)(As + (wm*64 + mt*16 + l16)*64 + (((ks*4+quad) ^ (l16&7))*8));
#pragma unroll
            for (int nt = 0; nt < 4; nt++) {
                int off = (wn*64 + nt*16 + l16)*64 + (((ks*4+quad) ^ (l16&7))*8);
                bkf[nt] = *(const bf16x8*)(Bk + off);
                bvf[nt] = *(const bf16x8*)(Bv + off);
            }
#pragma unroll
            for (int mt = 0; mt < 4; mt++)
#pragma unroll
                for (int nt = 0; nt < 4; nt++) {
                    ak[mt*4+nt] = __builtin_amdgcn_mfma_f32_16x16x32_bf16(af[mt], bkf[nt], ak[mt*4+nt], 0, 0, 0);
                    av[mt*4+nt] = __builtin_amdgcn_mfma_f32_16x16x32_bf16(af[mt], bvf[nt], av[mt*4+nt], 0, 0, 0);
                }
        }
        __syncthreads();
    }
#pragma unroll
    for (int mt = 0; mt < 4; mt++)
#pragma unroll
        for (int nt = 0; nt < 4; nt++) {
            int cc = wn*64 + nt*16 + l16;
            int rr0 = m0 + wm*64 + mt*16 + quad*4;
            int bb = rr0 >> 11, t0 = rr0 & 2047;
            // K' row-major, scale folded
#pragma unroll
            for (int r = 0; r < 4; r++)
                kpb[((size_t)((bb*16 + h)*2048 + t0 + r))*128 + cc] = f2bf(ak[mt*4+nt][r] * SC2);
            // V' transposed: 4 consecutive t per lane -> uint2
            ushort_t pk[4];
#pragma unroll
            for (int r = 0; r < 4; r++) pk[r] = f2bf(av[mt*4+nt][r]);
            *(uint2*)(vpT + ((size_t)((bb*16 + h)*128 + cc))*2048 + t0) = *(const uint2*)pk;
        }
}

// ---------------------------------------------------------------------------
__global__ __launch_bounds__(256) void prep_wb(const float* __restrict__ wkv_b,
                                               ushort_t* __restrict__ wbkN,
                                               ushort_t* __restrict__ wbvB)
{
    int u = blockIdx.x * 256 + threadIdx.x;
    int h = u >> 16, rem = u & 65535;
    wbkN[u] = f2bf(wkv_b[h*131072 + rem]);            // [h][d][c] natural rows
    wbvB[u] = f2bf(wkv_b[h*131072 + 65536 + rem]);
}

// ---------------------------------------------------------------------------
__global__ __launch_bounds__(256) void kv_norm_rope(const float* __restrict__ kvr,
                                                    const float* __restrict__ w,
                                                    const float* __restrict__ cosT,
                                                    const float* __restrict__ sinT,
                                                    ushort_t* __restrict__ kvnb,
                                                    ushort_t* __restrict__ kpeb)
{
    const int bs   = blockIdx.x * 4 + (threadIdx.x >> 6);
    const int lane = threadIdx.x & 63;
    const int s    = bs & (S_ - 1);
    const float* row = kvr + bs * 576;
    const float SC2 = 0.10411756512f;   // 192^-0.5 * log2(e) folded into k_pe

    float4 v0 = *(const float4*)(row + lane*8);
    float4 v1 = *(const float4*)(row + lane*8 + 4);
    float ss = v0.x*v0.x + v0.y*v0.y + v0.z*v0.z + v0.w*v0.w
             + v1.x*v1.x + v1.y*v1.y + v1.z*v1.z + v1.w*v1.w;
#pragma unroll
    for (int off = 32; off >= 1; off >>= 1) ss += __shfl_xor(ss, off);
    const float rs = rsqrtf(ss * (1.0f/512.0f) + 1e-6f);

    float4 w0 = *(const float4*)(w + lane*8);
    float4 w1 = *(const float4*)(w + lane*8 + 4);
    float o[8];
    o[0] = v0.x*rs*w0.x; o[1] = v0.y*rs*w0.y; o[2] = v0.z*rs*w0.z; o[3] = v0.w*rs*w0.w;
    o[4] = v1.x*rs*w1.x; o[5] = v1.y*rs*w1.y; o[6] = v1.z*rs*w1.z; o[7] = v1.w*rs*w1.w;

    ushort_t pk[8];
#pragma unroll
    for (int p = 0; p < 8; p++) pk[p] = f2bf(o[p]);
    *(uint4*)(kvnb + (size_t)bs*512 + lane*8) = *(const uint4*)pk;

    if (lane < 32) {
        float xr = row[512 + 2*lane], xi = row[512 + 2*lane + 1];
        float c  = cosT[s*32 + lane], sn = sinT[s*32 + lane];
        ushort_t p2[2] = { f2bf((xr*c - xi*sn)*SC2), f2bf((xr*sn + xi*c)*SC2) };
        *(uint_t*)(kpeb + (size_t)bs*64 + 2*lane) = *(const uint_t*)p2;
    }
}

// ---------------------------------------------------------------------------
// stage one 32-key tile: K'|kpe (12 frag-groups) -> F[buf], V' (8) -> V[buf].
// lane-linear frag layout; wave w issues its subset (20 groups / 8 waves).
// ---------------------------------------------------------------------------
__device__ __forceinline__ void stage_tile(const ushort_t* kp_h, const ushort_t* kpe_b,
                                           const ushort_t* vpT_h, ushort_t* ldsb,
                                           int t0, int buf, int w, int l16, int q8e)
{
    ushort_t* Fb = ldsb + buf*6144;
    ushort_t* Vb = ldsb + 12288 + buf*4096;
#pragma unroll
    for (int ii = 0; ii < 3; ii++) {
        int i = w + ii*8;
        if (i < 12) {
            int g2 = (i >= 6) ? 1 : 0;
            int ks = i - g2*6;
            int row = t0 + g2*16 + l16;
            const ushort_t* src = (ks < 4)
                ? (kp_h + (size_t)row*128 + ks*32 + q8e)
                : (kpe_b + (size_t)row*64 + (ks-4)*32 + q8e);
            gl_lds16(src, Fb + i*512);
        } else if (i < 20) {
            int gv = i - 12;
            const ushort_t* src = vpT_h + (size_t)(gv*16 + l16)*2048 + t0 + q8e;
            gl_lds16(src, Vb + gv*512);
        }
    }
}

// ---------------------------------------------------------------------------
// MFMA flash attention v13: K-absorbed, log2-domain softmax, cvt_pk P-pack,
// unmasked fast path. 128 q-rows/block, 8 waves x 16 rows, TK=32, qf[6],
// double-buffered 50 KB LDS, 1 barrier/tile.
// ---------------------------------------------------------------------------
__global__ __launch_bounds__(512, 2) void attn_mfma(
    const ushort_t* __restrict__ qb,
    const ushort_t* __restrict__ kpb,
    const ushort_t* __restrict__ kpeb,
    const ushort_t* __restrict__ vpT,
    const float* __restrict__ cosT,
    const float* __restrict__ sinT,
    ushort_t* __restrict__ ovb)
{
    // XCD/LPT swizzle: batch = flat&1, longest causal blocks first
    const int flat = blockIdx.x + 16*blockIdx.y + 256*blockIdx.z;
    const int b    = flat & 1;
    const int rem  = flat >> 1;
    const int h    = rem & 15;
    const int q0   = (15 - (rem >> 4)) << 7;

    const int tid  = threadIdx.x;
    const int w    = tid >> 6;
    const int lane = tid & 63;
    const int l16  = lane & 15;
    const int quad = lane >> 4;
    const int tl   = quad * 4;
    const int lb   = lane & 48;
    const int q8e  = quad * 8;

    // LDS map (ushort elems): F[buf]=buf*6144 (12KB x2); V[buf]=12288+buf*4096
    // (8KB x2); pt = 20480 + w*640. Total 25600 ushorts = 51200 B.
    __shared__ __align__(16) ushort_t lds[25600];

    const ushort_t* kp_h  = kpb + (size_t)(b*16 + h)*2048*128;
    const ushort_t* kpe_b = kpeb + (size_t)b*S_*64;
    const ushort_t* vpT_h = vpT + (size_t)(b*16 + h)*128*2048;

    const int r0    = q0 + w*16;
    const int rglob = r0 + l16;

    // ---- prologue: stage tile 0 into buf 0 (overlaps qf build)
    stage_tile(kp_h, kpe_b, vpT_h, lds, 0, 0, w, l16, q8e);

    // ===== qf[0..3] = q_nope frags (raw), qf[4..5] = rope(q_pe) (raw) =====
    const ushort_t* qrow = qb + (size_t)(b*S_ + rglob)*3072 + h*192;
    bf16x8 qf[6];
#pragma unroll
    for (int ks = 0; ks < 4; ks++)
        qf[ks] = *(const bf16x8*)(qrow + ks*32 + q8e);
#pragma unroll
    for (int kk = 0; kk < 2; kk++) {
        int off = kk*32 + q8e;
        uint4 pv4 = *(const uint4*)(qrow + 128 + off);
        const ushort_t* pe = (const ushort_t*)&pv4;
        ushort_t pk[8];
#pragma unroll
        for (int u2 = 0; u2 < 4; u2++) {
            float xr = bf2f(pe[2*u2]), xi = bf2f(pe[2*u2+1]);
            int pi = (off >> 1) + u2;
            float c = cosT[rglob*32 + pi], sn = sinT[rglob*32 + pi];
            pk[2*u2]   = f2bf(xr*c  - xi*sn);
            pk[2*u2+1] = f2bf(xr*sn + xi*c );
        }
        qf[4 + kk] = *(const bf16x8*)pk;
    }
    __syncthreads();   // tile0 staging drained

    // ===== flash main loop: TK=32, double-buffered, 1 barrier/tile =====
    f32x4 o[8];
#pragma unroll
    for (int n = 0; n < 8; n++) o[n] = (f32x4)(0.f);
    float m_s = -1e30f, l_s = 0.f;

    const int bniter = (q0 >> 5) + 4;            // block-uniform tile count
    const int wniter = ((r0 + 15) >> 5) + 1;     // this wave's causal bound
    ushort_t* ptw = lds + 20480 + w*640;
    int cur = 0;

#pragma unroll 1
    for (int it = 0; it < bniter; it++) {
        if (it + 1 < bniter)
            stage_tile(kp_h, kpe_b, vpT_h, lds, (it+1)*32, cur ^ 1, w, l16, q8e);

        if (it < wniter) {
            const int t0 = it * 32;
            const ushort_t* Fb = lds + cur*6144;
            const ushort_t* Vb = lds + 12288 + cur*4096;

            // S^T over 192 dims (log2 domain): C col = q-row, C row = key
            __builtin_amdgcn_s_setprio(1);
            f32x4 s0 = (f32x4)(0.f), s1 = (f32x4)(0.f);
#pragma unroll
            for (int ks = 0; ks < 6; ks++) {
                bf16x8 kf0 = *(const bf16x8*)(Fb + ks*512 + lane*8);
                s0 = __builtin_amdgcn_mfma_f32_16x16x32_bf16(kf0, qf[ks], s0, 0, 0, 0);
                bf16x8 kf1 = *(const bf16x8*)(Fb + 3072 + ks*512 + lane*8);
                s1 = __builtin_amdgcn_mfma_f32_16x16x32_bf16(kf1, qf[ks], s1, 0, 0, 0);
            }
            __builtin_amdgcn_s_setprio(0);

            // online softmax (log2 domain), unmasked fast path for full tiles
            float pv[8];
            if (t0 + 31 <= r0) {
#pragma unroll
                for (int reg = 0; reg < 4; reg++) { pv[reg] = s0[reg]; pv[4+reg] = s1[reg]; }
            } else {
#pragma unroll
                for (int reg = 0; reg < 4; reg++) {
                    pv[reg]   = ((t0 + tl + reg)      <= rglob) ? s0[reg] : -1e30f;
                    pv[4+reg] = ((t0 + 16 + tl + reg) <= rglob) ? s1[reg] : -1e30f;
                }
            }
            float mx = fmaxf(fmaxf(fmaxf(pv[0], pv[1]), fmaxf(pv[2], pv[3])),
                             fmaxf(fmaxf(pv[4], pv[5]), fmaxf(pv[6], pv[7])));
            mx = fmaxf(mx, __shfl_xor(mx, 16));
            mx = fmaxf(mx, __shfl_xor(mx, 32));
            if (!__all(mx <= m_s)) {        // exact skip when max unchanged
                float mn = fmaxf(m_s, mx);
                float al = exp2f(m_s - mn);
                m_s = mn;
                l_s *= al;
                f32x4 alv;
#pragma unroll
                for (int reg = 0; reg < 4; reg++) alv[reg] = __shfl(al, lb + tl + reg, 64);
#pragma unroll
                for (int n = 0; n < 8; n++) o[n] *= alv;
            }
            float ps = 0.f;
#pragma unroll
            for (int reg = 0; reg < 8; reg++) {
                pv[reg] = exp2f(pv[reg] - m_s);   // masked -> exact 0 (underflow)
                ps += pv[reg];
            }
            ps += __shfl_xor(ps, 16);
            ps += __shfl_xor(ps, 32);
            l_s += ps;

            // P-pack via v_cvt_pk_bf16_f32 (RNE, = f2bf) -> ptw, fence, A-frag
            uint_t c01, c23, c45, c67;
            asm("v_cvt_pk_bf16_f32 %0, %1, %2" : "=v"(c01) : "v"(pv[0]), "v"(pv[1]));
            asm("v_cvt_pk_bf16_f32 %0, %1, %2" : "=v"(c23) : "v"(pv[2]), "v"(pv[3]));
            asm("v_cvt_pk_bf16_f32 %0, %1, %2" : "=v"(c45) : "v"(pv[4]), "v"(pv[5]));
            asm("v_cvt_pk_bf16_f32 %0, %1, %2" : "=v"(c67) : "v"(pv[6]), "v"(pv[7]));
            uint2 plo; plo.x = c01; plo.y = c23;
            uint2 phi; phi.x = c45; phi.y = c67;
            *(uint2*)(ptw + l16*40 + tl)      = plo;
            *(uint2*)(ptw + l16*40 + 16 + tl) = phi;
            asm volatile("" ::: "memory");
            bf16x8 ap = *(const bf16x8*)(ptw + l16*40 + q8e);
            asm volatile("" ::: "memory");

            // PV': o[n] += P[r][t] * V'[t][c], c = n*16 + l16 (128-dim output)
            __builtin_amdgcn_s_setprio(1);
#pragma unroll
            for (int n = 0; n < 8; n++) {
                bf16x8 bv = *(const bf16x8*)(Vb + n*512 + lane*8);
                o[n] = __builtin_amdgcn_mfma_f32_16x16x32_bf16(ap, bv, o[n], 0, 0, 0);
            }
            __builtin_amdgcn_s_setprio(0);
        }
        __syncthreads();   // next-tile staging drained + cur-buffer reads done
        cur ^= 1;
    }

    // ===== output: ovb = o / l =====
    float linv = 1.f / l_s;
    f32x4 rlv;
#pragma unroll
    for (int reg = 0; reg < 4; reg++) rlv[reg] = __shfl(linv, lb + tl + reg, 64);

    ushort_t* orow = ovb + (size_t)(b*S_ + r0)*2048 + h*128;
#pragma unroll
    for (int n = 0; n < 8; n++)
#pragma unroll
        for (int reg = 0; reg < 4; reg++)
            orow[(size_t)(tl + reg)*2048 + n*16 + l16] = f2bf(o[n][reg] * rlv[reg]);
}

// ---------------------------------------------------------------------------
extern "C" void kernel_launch(void* const* d_in, const int* in_sizes, int n_in,
                              void* d_out, int out_size, void* d_ws, size_t ws_size,
                              hipStream_t stream) {
    const float* x     = (const float*)d_in[0];
    const float* cosT  = (const float*)d_in[1];
    const float* sinT  = (const float*)d_in[2];
    // d_in[3] mask: unused (causality applied directly)
    const float* wq    = (const float*)d_in[4];
    const float* wkv_a = (const float*)d_in[5];
    const float* kvw   = (const float*)d_in[6];
    const float* wkv_b = (const float*)d_in[7];
    const float* wo    = (const float*)d_in[8];
    float* out = (float*)d_out;

    ushort_t* qb   = (ushort_t*)d_ws;       // 4096x3072 bf16
    ushort_t* xb   = qb   + 12582912;       // 4096x2048 x-hi; later vpT
    ushort_t* wqb  = xb   + 8388608;        // 3072x2048; later wa_hi/wa_lo, then kpb
    ushort_t* wob  = wqb  + 6291456;        // 2048x2048 (cast AFTER attn; head = kpb tail)
    ushort_t* ovb  = wob  + 4194304;        // x-lo early; attn output later
    ushort_t* kvnb = ovb  + 8388608;        // 4096x512
    ushort_t* kpeb = kvnb + 2097152;        // 4096x64
    ushort_t* kvnT = kpeb + 262144;         // unused slot
    ushort_t* wbkN = kvnT + 2097152;        // 16x128x512 (natural layout)
    ushort_t* wbvB = wbkN + 1048576;        // 16x128x512
    float*    kvr  = (float*)(wbvB + 1048576);  // 4096x576 f32

    ushort_t* xlo  = ovb;                   // 4096x2048 bf16 (dead until attn)
    ushort_t* wahi = wqb;                   // 576x2048 bf16 (after q-proj)
    ushort_t* walo = wqb + 1179648;         // 576x2048 bf16
    ushort_t* vpT  = xb;                    // 2x16x128x2048 (after kv gemms)
    ushort_t* kpb  = wqb;                   // 2x16x2048x128 (after gemm_kv3; spills
                                            // 2097152 into wob head - wo cast later)

    dim3 blk(256);
    cast2_bf16<<<dim3(8192), blk, 0, stream>>>(x, xb, xlo, 8388608);
    cast_bf16<<<dim3(6144), blk, 0, stream>>>(wq, wqb, 6291456);
    prep_wb<<<dim3(4096), blk, 0, stream>>>(wkv_b, wbkN, wbvB);
    gemm_bf16<<<dim3(24, 32), blk, 0, stream>>>(xb, wqb, nullptr, qb, 4096, 3072, 2048, 3072, 3072, 1);
    cast2_bf16<<<dim3(1152), blk, 0, stream>>>(wkv_a, wahi, walo, 1179648);
    gemm_kv3<<<dim3(5, 32), blk, 0, stream>>>(xb, xlo, wahi, walo, kvr);
    kv_norm_rope<<<dim3(1024), blk, 0, stream>>>(kvr, kvw, cosT, sinT, kvnb, kpeb);
    gemm_vk<<<dim3(32, 16), blk, 0, stream>>>(kvnb, wbkN, wbvB, kpb, vpT);
    attn_mfma<<<dim3(16, 16, 2), dim3(512), 0, stream>>>(qb, kpb, kpeb, vpT, cosT, sinT, ovb);
    cast_bf16<<<dim3(4096), blk, 0, stream>>>(wo, wob, 4194304);
    gemm_bf16<<<dim3(16, 32), blk, 0, stream>>>(ovb, wob, out, nullptr, 4096, 2048, 2048, 2048, 2048, 0);
}